// Round 1
// baseline (1785.776 us; speedup 1.0000x reference)
//
#include <hip/hip_runtime.h>
#include <cmath>

#define NEG_SLOPE 0.2f
static constexpr int NGRAPH = 64;

// Monotone float -> uint map so unsigned atomicMax == float max.
__device__ __forceinline__ unsigned enc_f(float f) {
  unsigned u = __float_as_uint(f);
  return (u & 0x80000000u) ? ~u : (u | 0x80000000u);
}
__device__ __forceinline__ float dec_f(unsigned k) {
  unsigned u = (k & 0x80000000u) ? (k & 0x7FFFFFFFu) : ~k;
  return __uint_as_float(u);
}
// enc(-inf) = ~0xFF800000 = 0x007FFFFF
#define ENC_NEG_INF 0x007FFFFFu

// ---- layer-0 transform: h[n,c] = x[n] * W0[c] (Fin = 1), plus head dots ----
__global__ void transform0_kernel(const float* __restrict__ x,
                                  const float* __restrict__ W0,
                                  const float* __restrict__ a_src,
                                  const float* __restrict__ a_dst,
                                  float* __restrict__ h,
                                  float* __restrict__ as_,
                                  float* __restrict__ ad_,
                                  int n_nodes) {
  int lane = threadIdx.x & 63;
  int wave = (blockIdx.x * blockDim.x + threadIdx.x) >> 6;
  int nwaves = (gridDim.x * blockDim.x) >> 6;
  int head = lane >> 4, ch = lane & 15;
  float w0 = W0[lane];
  float asc = a_src[head * 16 + ch];
  float adc = a_dst[head * 16 + ch];
  for (int n = wave; n < n_nodes; n += nwaves) {
    float v = x[n] * w0;
    h[n * 64 + lane] = v;
    float s = v * asc, d = v * adc;
#pragma unroll
    for (int off = 8; off; off >>= 1) {
      s += __shfl_down(s, off, 16);
      d += __shfl_down(d, off, 16);
    }
    if (ch == 0) { as_[n * 4 + head] = s; ad_[n * 4 + head] = d; }
  }
}

// ---- hidden-layer transform: h_out = h_in @ W (64x64), plus head dots ----
// wave-per-node; W staged in LDS; row broadcast via shuffles.
__global__ void transform_kernel(const float* __restrict__ hin,
                                 const float* __restrict__ W,
                                 const float* __restrict__ a_src,
                                 const float* __restrict__ a_dst,
                                 float* __restrict__ hout,
                                 float* __restrict__ as_,
                                 float* __restrict__ ad_,
                                 int n_nodes) {
  __shared__ float Wlds[64 * 64];
  for (int i = threadIdx.x; i < 64 * 64; i += blockDim.x) Wlds[i] = W[i];
  __syncthreads();
  int lane = threadIdx.x & 63;
  int wave = (blockIdx.x * blockDim.x + threadIdx.x) >> 6;
  int nwaves = (gridDim.x * blockDim.x) >> 6;
  int head = lane >> 4, ch = lane & 15;
  float asc = a_src[head * 16 + ch];
  float adc = a_dst[head * 16 + ch];
  for (int n = wave; n < n_nodes; n += nwaves) {
    float hv = hin[n * 64 + lane];
    float acc = 0.f;
#pragma unroll
    for (int k = 0; k < 64; ++k) {
      float hk = __shfl(hv, k, 64);
      acc = fmaf(hk, Wlds[k * 64 + lane], acc);
    }
    hout[n * 64 + lane] = acc;
    float s = acc * asc, d = acc * adc;
#pragma unroll
    for (int off = 8; off; off >>= 1) {
      s += __shfl_down(s, off, 16);
      d += __shfl_down(d, off, 16);
    }
    if (ch == 0) { as_[n * 4 + head] = s; ad_[n * 4 + head] = d; }
  }
}

// ---- zero accumulators / z, set max to -inf (ws is poisoned every call) ----
__global__ void init_kernel(float* __restrict__ acc, float* __restrict__ z,
                            unsigned* __restrict__ menc, int n_nodes) {
  int i = blockIdx.x * blockDim.x + threadIdx.x;
  if (i < n_nodes * 64) acc[i] = 0.f;
  if (i < n_nodes * 4) { z[i] = 0.f; menc[i] = ENC_NEG_INF; }
}

// ---- edge pass 1: segment max of leaky_relu(as[src]+ad[dst]) over dst ----
__global__ void edge_max_kernel(const int* __restrict__ src,
                                const int* __restrict__ dst,
                                const float* __restrict__ as_,
                                const float* __restrict__ ad_,
                                unsigned* __restrict__ menc,
                                int nedge_real, int nedge_tot) {
  int e = blockIdx.x * blockDim.x + threadIdx.x;
  if (e >= nedge_tot) return;
  int s, d;
  if (e < nedge_real) { s = src[e]; d = dst[e]; } else { s = e - nedge_real; d = s; }
  const float4 a = *(const float4*)(as_ + s * 4);
  const float4 b = *(const float4*)(ad_ + d * 4);
  float e0 = a.x + b.x; e0 = e0 > 0.f ? e0 : NEG_SLOPE * e0;
  float e1 = a.y + b.y; e1 = e1 > 0.f ? e1 : NEG_SLOPE * e1;
  float e2 = a.z + b.z; e2 = e2 > 0.f ? e2 : NEG_SLOPE * e2;
  float e3 = a.w + b.w; e3 = e3 > 0.f ? e3 : NEG_SLOPE * e3;
  atomicMax(&menc[d * 4 + 0], enc_f(e0));
  atomicMax(&menc[d * 4 + 1], enc_f(e1));
  atomicMax(&menc[d * 4 + 2], enc_f(e2));
  atomicMax(&menc[d * 4 + 3], enc_f(e3));
}

// ---- edge pass 2: w = exp(e - m[dst]); z[dst,h] += w; acc[dst,:] += w*h[src,:]
// One wave per edge; lane c handles feature c (head = c/16).
__global__ void edge_acc_kernel(const int* __restrict__ src,
                                const int* __restrict__ dst,
                                const float* __restrict__ as_,
                                const float* __restrict__ ad_,
                                const unsigned* __restrict__ menc,
                                const float* __restrict__ h,
                                float* __restrict__ z,
                                float* __restrict__ acc,
                                int nedge_real, int nedge_tot) {
  int lane = threadIdx.x & 63;
  int wave = (blockIdx.x * blockDim.x + threadIdx.x) >> 6;
  if (wave >= nedge_tot) return;
  int s, d;
  if (wave < nedge_real) { s = src[wave]; d = dst[wave]; } else { s = wave - nedge_real; d = s; }
  int head = lane >> 4;
  float ev = as_[s * 4 + head] + ad_[d * 4 + head];
  ev = ev > 0.f ? ev : NEG_SLOPE * ev;
  float m = dec_f(menc[d * 4 + head]);
  float w = expf(ev - m);
  if ((lane & 15) == 0) atomicAdd(&z[d * 4 + head], w);
  atomicAdd(&acc[d * 64 + lane], w * h[s * 64 + lane]);
}

// ---- finalize: h' = acc / z + bias ----
__global__ void finalize_kernel(const float* __restrict__ z,
                                const float* __restrict__ bias,
                                float* __restrict__ acc, int n_nodes) {
  int i = blockIdx.x * blockDim.x + threadIdx.x;
  if (i >= n_nodes * 64) return;
  int c = i & 63;
  int n = i >> 6;
  acc[i] = acc[i] / z[n * 4 + (c >> 4)] + bias[c];
}

__global__ void zero_pool_kernel(float* __restrict__ pool, float* __restrict__ cnt) {
  int i = blockIdx.x * blockDim.x + threadIdx.x;
  if (i < NGRAPH * 64) pool[i] = 0.f;
  if (i < NGRAPH) cnt[i] = 0.f;
}

// ---- mean-pool: batch is sorted, so accumulate per contiguous segment ----
__global__ void pool_kernel(const float* __restrict__ h,
                            const int* __restrict__ batch,
                            float* __restrict__ pool,
                            float* __restrict__ cnt, int n_nodes) {
  int lane = threadIdx.x & 63;
  int wave = (blockIdx.x * blockDim.x + threadIdx.x) >> 6;
  int n0 = wave * 64;
  if (n0 >= n_nodes) return;
  int n1 = min(n0 + 64, n_nodes);
  int gcur = batch[n0];
  float acc = 0.f, c_acc = 0.f;
  for (int n = n0; n < n1; ++n) {
    int g = batch[n];
    if (g != gcur) {
      atomicAdd(&pool[gcur * 64 + lane], acc);
      if (lane == 0) atomicAdd(&cnt[gcur], c_acc);
      acc = 0.f; c_acc = 0.f; gcur = g;
    }
    acc += h[n * 64 + lane];
    c_acc += 1.f;
  }
  atomicAdd(&pool[gcur * 64 + lane], acc);
  if (lane == 0) atomicAdd(&cnt[gcur], c_acc);
}

// ---- final linear: out[g,o] = sum_c (pool[g,c]/cnt[g]) * Wf[c,o] + bf[o] ----
__global__ void final_kernel(const float* __restrict__ pool,
                             const float* __restrict__ cnt,
                             const float* __restrict__ Wf,
                             const float* __restrict__ bf,
                             float* __restrict__ out) {
  int g = blockIdx.x;
  int o = threadIdx.x;
  if (o >= 5) return;
  float cg = cnt[g];
  cg = cg > 1.f ? cg : 1.f;
  float acc = bf[o];
  for (int c = 0; c < 64; ++c)
    acc += (pool[g * 64 + c] / cg) * Wf[c * 5 + o];
  out[g * 5 + o] = acc;
}

extern "C" void kernel_launch(void* const* d_in, const int* in_sizes, int n_in,
                              void* d_out, int out_size, void* d_ws, size_t ws_size,
                              hipStream_t stream) {
  const float* x     = (const float*)d_in[0];
  const int*   ei    = (const int*)d_in[1];
  const int*   batch = (const int*)d_in[2];
  const float* W0    = (const float*)d_in[3];
  const float* as0   = (const float*)d_in[4];
  const float* ad0   = (const float*)d_in[5];
  const float* b0    = (const float*)d_in[6];
  const float* Wh    = (const float*)d_in[7];
  const float* ash   = (const float*)d_in[8];
  const float* adh   = (const float*)d_in[9];
  const float* bh    = (const float*)d_in[10];
  const float* Wf    = (const float*)d_in[11];
  const float* bf    = (const float*)d_in[12];
  float* out = (float*)d_out;

  const int N = in_sizes[0];       // 50000 (x is [N,1])
  const int E = in_sizes[1] / 2;   // 800000
  const int* src = ei;
  const int* dst = ei + E;
  const int nE = E + N;            // with self-loops

  // workspace layout (fp32 words)
  float* ws  = (float*)d_ws;
  float* hA  = ws;                          // N*64  transformed features
  float* hB  = hA + (size_t)N * 64;         // N*64  aggregate / layer output
  float* asb = hB + (size_t)N * 64;         // N*4
  float* adb = asb + (size_t)N * 4;         // N*4
  float* z   = adb + (size_t)N * 4;         // N*4
  unsigned* menc = (unsigned*)(z + (size_t)N * 4);  // N*4
  float* pool = (float*)(menc + (size_t)N * 4);     // 64*64
  float* cnt  = pool + NGRAPH * 64;                 // 64

  const int nodeElemBlocks = (N * 64 + 255) / 256;
  const int edgeBlocks     = (nE + 255) / 256;
  const int edgeWaveBlocks = (nE + 3) / 4;  // 4 waves per 256-thread block
  const int poolWaves      = (N + 63) / 64;
  const int poolBlocks     = (poolWaves + 3) / 4;

  for (int layer = 0; layer < 4; ++layer) {
    if (layer == 0) {
      transform0_kernel<<<2048, 256, 0, stream>>>(x, W0, as0, ad0, hA, asb, adb, N);
    } else {
      transform_kernel<<<2048, 256, 0, stream>>>(hB, Wh + (size_t)(layer - 1) * 64 * 64,
                                                 ash + (layer - 1) * 64, adh + (layer - 1) * 64,
                                                 hA, asb, adb, N);
    }
    init_kernel<<<nodeElemBlocks, 256, 0, stream>>>(hB, z, menc, N);
    edge_max_kernel<<<edgeBlocks, 256, 0, stream>>>(src, dst, asb, adb, menc, E, nE);
    edge_acc_kernel<<<edgeWaveBlocks, 256, 0, stream>>>(src, dst, asb, adb, menc, hA, z, hB, E, nE);
    const float* bias = (layer == 0) ? b0 : (bh + (layer - 1) * 64);
    finalize_kernel<<<nodeElemBlocks, 256, 0, stream>>>(z, bias, hB, N);
  }

  zero_pool_kernel<<<(NGRAPH * 64 + 255) / 256, 256, 0, stream>>>(pool, cnt);
  pool_kernel<<<poolBlocks, 256, 0, stream>>>(hB, batch, pool, cnt, N);
  final_kernel<<<NGRAPH, 64, 0, stream>>>(pool, cnt, Wf, bf, out);
}

// Round 2
// 680.444 us; speedup vs baseline: 2.6244x; 2.6244x over previous
//
#include <hip/hip_runtime.h>
#include <cmath>

#define NEG_SLOPE 0.2f
static constexpr int NGRAPH = 64;

__device__ __forceinline__ float lrelu(float x) {
  return x > 0.f ? x : NEG_SLOPE * x;
}

// ---- layer-0 transform: h[n,c] = x[n] * W0[c] (Fin = 1), plus head dots ----
__global__ void transform0_kernel(const float* __restrict__ x,
                                  const float* __restrict__ W0,
                                  const float* __restrict__ a_src,
                                  const float* __restrict__ a_dst,
                                  float* __restrict__ h,
                                  float* __restrict__ as_,
                                  float* __restrict__ ad_,
                                  int n_nodes) {
  int lane = threadIdx.x & 63;
  int wave = (blockIdx.x * blockDim.x + threadIdx.x) >> 6;
  int nwaves = (gridDim.x * blockDim.x) >> 6;
  int head = lane >> 4, ch = lane & 15;
  float w0 = W0[lane];
  float asc = a_src[head * 16 + ch];
  float adc = a_dst[head * 16 + ch];
  for (int n = wave; n < n_nodes; n += nwaves) {
    float v = x[n] * w0;
    h[n * 64 + lane] = v;
    float s = v * asc, d = v * adc;
#pragma unroll
    for (int off = 8; off; off >>= 1) {
      s += __shfl_down(s, off, 16);
      d += __shfl_down(d, off, 16);
    }
    if (ch == 0) { as_[n * 4 + head] = s; ad_[n * 4 + head] = d; }
  }
}

// ---- hidden-layer transform: h_out = h_in @ W (64x64), plus head dots ----
__global__ void transform_kernel(const float* __restrict__ hin,
                                 const float* __restrict__ W,
                                 const float* __restrict__ a_src,
                                 const float* __restrict__ a_dst,
                                 float* __restrict__ hout,
                                 float* __restrict__ as_,
                                 float* __restrict__ ad_,
                                 int n_nodes) {
  __shared__ float Wlds[64 * 64];
  for (int i = threadIdx.x; i < 64 * 64; i += blockDim.x) Wlds[i] = W[i];
  __syncthreads();
  int lane = threadIdx.x & 63;
  int wave = (blockIdx.x * blockDim.x + threadIdx.x) >> 6;
  int nwaves = (gridDim.x * blockDim.x) >> 6;
  int head = lane >> 4, ch = lane & 15;
  float asc = a_src[head * 16 + ch];
  float adc = a_dst[head * 16 + ch];
  for (int n = wave; n < n_nodes; n += nwaves) {
    float hv = hin[n * 64 + lane];
    float acc = 0.f;
#pragma unroll
    for (int k = 0; k < 64; ++k) {
      float hk = __shfl(hv, k, 64);
      acc = fmaf(hk, Wlds[k * 64 + lane], acc);
    }
    hout[n * 64 + lane] = acc;
    float s = acc * asc, d = acc * adc;
#pragma unroll
    for (int off = 8; off; off >>= 1) {
      s += __shfl_down(s, off, 16);
      d += __shfl_down(d, off, 16);
    }
    if (ch == 0) { as_[n * 4 + head] = s; ad_[n * 4 + head] = d; }
  }
}

// ================= CSR build (once per call; edges fixed across layers) =====

__global__ void deg_init_kernel(int* __restrict__ counts, int n_nodes) {
  int i = blockIdx.x * blockDim.x + threadIdx.x;
  if (i < n_nodes) counts[i] = 1;  // self-loop
}

__global__ void deg_count_kernel(const int* __restrict__ dst,
                                 int* __restrict__ counts, int nedge) {
  int e = blockIdx.x * blockDim.x + threadIdx.x;
  if (e < nedge) atomicAdd(&counts[dst[e]], 1);
}

// per-block exclusive scan (block = 256)
__global__ void scan1_kernel(const int* __restrict__ counts,
                             int* __restrict__ scanned,
                             int* __restrict__ blockSums, int n) {
  __shared__ int tmp[256];
  int i = blockIdx.x * 256 + threadIdx.x;
  int v = (i < n) ? counts[i] : 0;
  tmp[threadIdx.x] = v;
  __syncthreads();
#pragma unroll
  for (int off = 1; off < 256; off <<= 1) {
    int t = (threadIdx.x >= off) ? tmp[threadIdx.x - off] : 0;
    __syncthreads();
    tmp[threadIdx.x] += t;
    __syncthreads();
  }
  if (i < n) scanned[i] = tmp[threadIdx.x] - v;  // exclusive
  if (threadIdx.x == 255) blockSums[blockIdx.x] = tmp[255];
}

// single-block exclusive scan of block sums (nblocks <= 256)
__global__ void scan2_kernel(int* __restrict__ blockSums, int nblocks) {
  __shared__ int tmp[256];
  int v = (threadIdx.x < nblocks) ? blockSums[threadIdx.x] : 0;
  tmp[threadIdx.x] = v;
  __syncthreads();
#pragma unroll
  for (int off = 1; off < 256; off <<= 1) {
    int t = (threadIdx.x >= off) ? tmp[threadIdx.x - off] : 0;
    __syncthreads();
    tmp[threadIdx.x] += t;
    __syncthreads();
  }
  if (threadIdx.x < nblocks) blockSums[threadIdx.x] = tmp[threadIdx.x] - v;
}

// offsets = scanned + blockOffset; cursor = offsets+1; plant self-loop edge.
__global__ void scan3_kernel(const int* __restrict__ scanned,
                             const int* __restrict__ blockSums,
                             int* __restrict__ offsets,
                             int* __restrict__ cursor,
                             int* __restrict__ csr, int n) {
  int i = blockIdx.x * 256 + threadIdx.x;
  if (i >= n) return;
  int off = scanned[i] + blockSums[blockIdx.x];
  offsets[i] = off;
  cursor[i] = off + 1;
  csr[off] = i;  // self edge occupies slot 0 of each row
}

__global__ void scatter_kernel(const int* __restrict__ src,
                               const int* __restrict__ dst,
                               int* __restrict__ cursor,
                               int* __restrict__ csr, int nedge) {
  int e = blockIdx.x * blockDim.x + threadIdx.x;
  if (e >= nedge) return;
  int pos = atomicAdd(&cursor[dst[e]], 1);
  csr[pos] = src[e];
}

// ========== fused segment max + softmax + weighted gather, wave/node ========
__global__ void aggregate_kernel(const int* __restrict__ offsets,
                                 const int* __restrict__ counts,
                                 const int* __restrict__ csr,
                                 const float* __restrict__ as_,
                                 const float* __restrict__ ad_,
                                 const float* __restrict__ h,
                                 const float* __restrict__ bias,
                                 float* __restrict__ hout, int n_nodes) {
  int lane = threadIdx.x & 63;
  int node = (blockIdx.x * blockDim.x + threadIdx.x) >> 6;
  if (node >= n_nodes) return;
  int row = offsets[node];
  int deg = counts[node];
  int head = lane >> 4;
  const float4 ad4 = *(const float4*)(ad_ + node * 4);

  // pass A: per-head segment max of leaky_relu(as[src]+ad[dst])
  float m0 = -INFINITY, m1 = -INFINITY, m2 = -INFINITY, m3 = -INFINITY;
  for (int base = 0; base < deg; base += 64) {
    int idx = base + lane;
    if (idx < deg) {
      int s = csr[row + idx];
      const float4 a4 = *(const float4*)(as_ + s * 4);
      m0 = fmaxf(m0, lrelu(a4.x + ad4.x));
      m1 = fmaxf(m1, lrelu(a4.y + ad4.y));
      m2 = fmaxf(m2, lrelu(a4.z + ad4.z));
      m3 = fmaxf(m3, lrelu(a4.w + ad4.w));
    }
  }
#pragma unroll
  for (int off = 32; off; off >>= 1) {
    m0 = fmaxf(m0, __shfl_xor(m0, off));
    m1 = fmaxf(m1, __shfl_xor(m1, off));
    m2 = fmaxf(m2, __shfl_xor(m2, off));
    m3 = fmaxf(m3, __shfl_xor(m3, off));
  }

  // pass B: w = exp(e-m); z += w; acc[c] += w * h[src, c]
  float z0 = 0.f, z1 = 0.f, z2 = 0.f, z3 = 0.f;
  float acc = 0.f;
  for (int base = 0; base < deg; base += 64) {
    int idx = base + lane;
    int s = 0;
    float w0 = 0.f, w1 = 0.f, w2 = 0.f, w3 = 0.f;
    if (idx < deg) {
      s = csr[row + idx];
      const float4 a4 = *(const float4*)(as_ + s * 4);
      w0 = __expf(lrelu(a4.x + ad4.x) - m0);
      w1 = __expf(lrelu(a4.y + ad4.y) - m1);
      w2 = __expf(lrelu(a4.z + ad4.z) - m2);
      w3 = __expf(lrelu(a4.w + ad4.w) - m3);
    }
    z0 += w0; z1 += w1; z2 += w2; z3 += w3;
    int cnt = min(64, deg - base);
    for (int j = 0; j < cnt; ++j) {
      int sj = __shfl(s, j);
      float wx = __shfl(w0, j);
      float wy = __shfl(w1, j);
      float wz = __shfl(w2, j);
      float ww = __shfl(w3, j);
      float wj = head == 0 ? wx : head == 1 ? wy : head == 2 ? wz : ww;
      acc = fmaf(wj, h[(size_t)sj * 64 + lane], acc);
    }
  }
#pragma unroll
  for (int off = 32; off; off >>= 1) {
    z0 += __shfl_xor(z0, off);
    z1 += __shfl_xor(z1, off);
    z2 += __shfl_xor(z2, off);
    z3 += __shfl_xor(z3, off);
  }
  float zsel = head == 0 ? z0 : head == 1 ? z1 : head == 2 ? z2 : z3;
  hout[(size_t)node * 64 + lane] = acc / zsel + bias[lane];
}

// =============================== pooling ====================================

__global__ void zero_pool_kernel(float* __restrict__ pool, float* __restrict__ cnt) {
  int i = blockIdx.x * blockDim.x + threadIdx.x;
  if (i < NGRAPH * 64) pool[i] = 0.f;
  if (i < NGRAPH) cnt[i] = 0.f;
}

__global__ void pool_kernel(const float* __restrict__ h,
                            const int* __restrict__ batch,
                            float* __restrict__ pool,
                            float* __restrict__ cnt, int n_nodes) {
  int lane = threadIdx.x & 63;
  int wave = (blockIdx.x * blockDim.x + threadIdx.x) >> 6;
  int n0 = wave * 64;
  if (n0 >= n_nodes) return;
  int n1 = min(n0 + 64, n_nodes);
  int gcur = batch[n0];
  float acc = 0.f, c_acc = 0.f;
  for (int n = n0; n < n1; ++n) {
    int g = batch[n];
    if (g != gcur) {
      atomicAdd(&pool[gcur * 64 + lane], acc);
      if (lane == 0) atomicAdd(&cnt[gcur], c_acc);
      acc = 0.f; c_acc = 0.f; gcur = g;
    }
    acc += h[(size_t)n * 64 + lane];
    c_acc += 1.f;
  }
  atomicAdd(&pool[gcur * 64 + lane], acc);
  if (lane == 0) atomicAdd(&cnt[gcur], c_acc);
}

__global__ void final_kernel(const float* __restrict__ pool,
                             const float* __restrict__ cnt,
                             const float* __restrict__ Wf,
                             const float* __restrict__ bf,
                             float* __restrict__ out) {
  int g = blockIdx.x;
  int o = threadIdx.x;
  if (o >= 5) return;
  float cg = cnt[g];
  cg = cg > 1.f ? cg : 1.f;
  float acc = bf[o];
  for (int c = 0; c < 64; ++c)
    acc += (pool[g * 64 + c] / cg) * Wf[c * 5 + o];
  out[g * 5 + o] = acc;
}

extern "C" void kernel_launch(void* const* d_in, const int* in_sizes, int n_in,
                              void* d_out, int out_size, void* d_ws, size_t ws_size,
                              hipStream_t stream) {
  const float* x     = (const float*)d_in[0];
  const int*   ei    = (const int*)d_in[1];
  const int*   batch = (const int*)d_in[2];
  const float* W0    = (const float*)d_in[3];
  const float* as0   = (const float*)d_in[4];
  const float* ad0   = (const float*)d_in[5];
  const float* b0    = (const float*)d_in[6];
  const float* Wh    = (const float*)d_in[7];
  const float* ash   = (const float*)d_in[8];
  const float* adh   = (const float*)d_in[9];
  const float* bh    = (const float*)d_in[10];
  const float* Wf    = (const float*)d_in[11];
  const float* bf    = (const float*)d_in[12];
  float* out = (float*)d_out;

  const int N = in_sizes[0];       // 50000
  const int E = in_sizes[1] / 2;   // 800000
  const int* src = ei;
  const int* dst = ei + E;
  const int nE = E + N;            // with self-loops

  // workspace layout
  float* ws  = (float*)d_ws;
  float* hA  = ws;                            // N*64
  float* hB  = hA + (size_t)N * 64;           // N*64
  float* asb = hB + (size_t)N * 64;           // N*4
  float* adb = asb + (size_t)N * 4;           // N*4
  int* counts   = (int*)(adb + (size_t)N * 4);  // N
  int* offsets  = counts + N;                   // N
  int* cursor   = offsets + N;                  // N
  int* scanned  = cursor + N;                   // N
  int* blockSums = scanned + N;                 // 256
  int* csr      = blockSums + 256;              // nE
  float* pool   = (float*)(csr + nE);           // 64*64
  float* cnt    = pool + NGRAPH * 64;           // 64

  const int nodeBlocks  = (N + 255) / 256;       // scan blocks (196)
  const int edgeBlocks  = (E + 255) / 256;
  const int nodeWaveBlocks = (N + 3) / 4;        // wave-per-node kernels
  const int poolWaves   = (N + 63) / 64;
  const int poolBlocks  = (poolWaves + 3) / 4;

  // ---- build CSR by dst (once; reused for all 4 layers) ----
  deg_init_kernel<<<nodeBlocks, 256, 0, stream>>>(counts, N);
  deg_count_kernel<<<edgeBlocks, 256, 0, stream>>>(dst, counts, E);
  scan1_kernel<<<nodeBlocks, 256, 0, stream>>>(counts, scanned, blockSums, N);
  scan2_kernel<<<1, 256, 0, stream>>>(blockSums, nodeBlocks);
  scan3_kernel<<<nodeBlocks, 256, 0, stream>>>(scanned, blockSums, offsets, cursor, csr, N);
  scatter_kernel<<<edgeBlocks, 256, 0, stream>>>(src, dst, cursor, csr, E);

  for (int layer = 0; layer < 4; ++layer) {
    if (layer == 0) {
      transform0_kernel<<<2048, 256, 0, stream>>>(x, W0, as0, ad0, hA, asb, adb, N);
    } else {
      transform_kernel<<<2048, 256, 0, stream>>>(hB, Wh + (size_t)(layer - 1) * 64 * 64,
                                                 ash + (layer - 1) * 64, adh + (layer - 1) * 64,
                                                 hA, asb, adb, N);
    }
    const float* bias = (layer == 0) ? b0 : (bh + (layer - 1) * 64);
    aggregate_kernel<<<nodeWaveBlocks, 256, 0, stream>>>(offsets, counts, csr,
                                                         asb, adb, hA, bias, hB, N);
  }

  zero_pool_kernel<<<(NGRAPH * 64 + 255) / 256, 256, 0, stream>>>(pool, cnt);
  pool_kernel<<<poolBlocks, 256, 0, stream>>>(hB, batch, pool, cnt, N);
  final_kernel<<<NGRAPH, 64, 0, stream>>>(pool, cnt, Wf, bf, out);
}

// Round 3
// 440.915 us; speedup vs baseline: 4.0502x; 1.5433x over previous
//
#include <hip/hip_runtime.h>
#include <cmath>

#define NEG_SLOPE 0.2f
static constexpr int NGRAPH = 64;

__device__ __forceinline__ float lrelu(float x) {
  return x > 0.f ? x : NEG_SLOPE * x;
}

// ---- layer-0 transform: h[n,c] = x[n] * W0[c] (Fin = 1), plus head dots ----
__global__ void transform0_kernel(const float* __restrict__ x,
                                  const float* __restrict__ W0,
                                  const float* __restrict__ a_src,
                                  const float* __restrict__ a_dst,
                                  float* __restrict__ h,
                                  float* __restrict__ as_,
                                  float* __restrict__ ad_,
                                  int n_nodes) {
  int lane = threadIdx.x & 63;
  int wave = (blockIdx.x * blockDim.x + threadIdx.x) >> 6;
  int nwaves = (gridDim.x * blockDim.x) >> 6;
  int head = lane >> 4, ch = lane & 15;
  float w0 = W0[lane];
  float asc = a_src[head * 16 + ch];
  float adc = a_dst[head * 16 + ch];
  for (int n = wave; n < n_nodes; n += nwaves) {
    float v = x[n] * w0;
    h[(size_t)n * 64 + lane] = v;
    float s = v * asc, d = v * adc;
#pragma unroll
    for (int off = 8; off; off >>= 1) {
      s += __shfl_down(s, off, 16);
      d += __shfl_down(d, off, 16);
    }
    if (ch == 0) { as_[n * 4 + head] = s; ad_[n * 4 + head] = d; }
  }
}

// ---- hidden-layer transform: h_out = h_in @ W (64x64), plus head dots ----
// W column `lane` lives in 64 VGPRs; h-row fetched via wave-uniform scalar
// loads (readfirstlane forces s_load), so per node = 16 SMEM + 64 v_fmac.
__global__ void transform_kernel(const float* __restrict__ hin,
                                 const float* __restrict__ W,
                                 const float* __restrict__ a_src,
                                 const float* __restrict__ a_dst,
                                 float* __restrict__ hout,
                                 float* __restrict__ as_,
                                 float* __restrict__ ad_,
                                 int n_nodes) {
  int lane = threadIdx.x & 63;
  int wave = (blockIdx.x * blockDim.x + threadIdx.x) >> 6;
  int nwaves = (gridDim.x * blockDim.x) >> 6;
  int head = lane >> 4, ch = lane & 15;
  float wreg[64];
#pragma unroll
  for (int k = 0; k < 64; ++k) wreg[k] = W[k * 64 + lane];
  float asc = a_src[head * 16 + ch];
  float adc = a_dst[head * 16 + ch];
  for (int n = wave; n < n_nodes; n += nwaves) {
    int nu = __builtin_amdgcn_readfirstlane(n);
    const float* hrow = hin + (size_t)nu * 64;
    float acc = 0.f;
#pragma unroll
    for (int k = 0; k < 64; ++k) acc = fmaf(hrow[k], wreg[k], acc);
    hout[(size_t)nu * 64 + lane] = acc;
    float s = acc * asc, d = acc * adc;
#pragma unroll
    for (int off = 8; off; off >>= 1) {
      s += __shfl_down(s, off, 16);
      d += __shfl_down(d, off, 16);
    }
    if (ch == 0) { as_[nu * 4 + head] = s; ad_[nu * 4 + head] = d; }
  }
}

// ================= CSR build (once per call; edges fixed across layers) =====

__global__ void deg_init_kernel(int* __restrict__ counts, int n_nodes) {
  int i = blockIdx.x * blockDim.x + threadIdx.x;
  if (i < n_nodes) counts[i] = 1;  // self-loop
}

__global__ void deg_count_kernel(const int* __restrict__ dst,
                                 int* __restrict__ counts, int nedge) {
  int e = blockIdx.x * blockDim.x + threadIdx.x;
  if (e < nedge) atomicAdd(&counts[dst[e]], 1);
}

__global__ void scan1_kernel(const int* __restrict__ counts,
                             int* __restrict__ scanned,
                             int* __restrict__ blockSums, int n) {
  __shared__ int tmp[256];
  int i = blockIdx.x * 256 + threadIdx.x;
  int v = (i < n) ? counts[i] : 0;
  tmp[threadIdx.x] = v;
  __syncthreads();
#pragma unroll
  for (int off = 1; off < 256; off <<= 1) {
    int t = (threadIdx.x >= off) ? tmp[threadIdx.x - off] : 0;
    __syncthreads();
    tmp[threadIdx.x] += t;
    __syncthreads();
  }
  if (i < n) scanned[i] = tmp[threadIdx.x] - v;  // exclusive
  if (threadIdx.x == 255) blockSums[blockIdx.x] = tmp[255];
}

__global__ void scan2_kernel(int* __restrict__ blockSums, int nblocks) {
  __shared__ int tmp[256];
  int v = (threadIdx.x < nblocks) ? blockSums[threadIdx.x] : 0;
  tmp[threadIdx.x] = v;
  __syncthreads();
#pragma unroll
  for (int off = 1; off < 256; off <<= 1) {
    int t = (threadIdx.x >= off) ? tmp[threadIdx.x - off] : 0;
    __syncthreads();
    tmp[threadIdx.x] += t;
    __syncthreads();
  }
  if (threadIdx.x < nblocks) blockSums[threadIdx.x] = tmp[threadIdx.x] - v;
}

__global__ void scan3_kernel(const int* __restrict__ scanned,
                             const int* __restrict__ blockSums,
                             int* __restrict__ offsets,
                             int* __restrict__ cursor,
                             int* __restrict__ csr, int n) {
  int i = blockIdx.x * 256 + threadIdx.x;
  if (i >= n) return;
  int off = scanned[i] + blockSums[blockIdx.x];
  offsets[i] = off;
  cursor[i] = off + 1;
  csr[off] = i;  // self edge occupies slot 0 of each row
}

__global__ void scatter_kernel(const int* __restrict__ src,
                               const int* __restrict__ dst,
                               int* __restrict__ cursor,
                               int* __restrict__ csr, int nedge) {
  int e = blockIdx.x * blockDim.x + threadIdx.x;
  if (e >= nedge) return;
  int pos = atomicAdd(&cursor[dst[e]], 1);
  csr[pos] = src[e];
}

// ========== fused segment max + softmax + weighted gather, wave/node ========
// Per 64-edge chunk: lanes compute {src, w[4 heads]} and stash them in LDS;
// the serial gather loop then reads int4/float4 BROADCASTS (2 ds_read_b128
// per 4 edges) and keeps 4 gathers in flight.
__global__ void aggregate_kernel(const int* __restrict__ offsets,
                                 const int* __restrict__ counts,
                                 const int* __restrict__ csr,
                                 const float* __restrict__ as_,
                                 const float* __restrict__ ad_,
                                 const float* __restrict__ h,
                                 const float* __restrict__ bias,
                                 float* __restrict__ hout, int n_nodes) {
  __shared__ int lds_s[4][64];
  __shared__ float lds_w[4][4 * 64];
  int lane = threadIdx.x & 63;
  int wv = threadIdx.x >> 6;
  int node = (blockIdx.x * blockDim.x + threadIdx.x) >> 6;
  if (node >= n_nodes) return;
  int row = offsets[node];
  int deg = counts[node];
  int head = lane >> 4;
  const float4 ad4 = *(const float4*)(ad_ + node * 4);

  // pass A: per-head segment max
  float m0 = -INFINITY, m1 = -INFINITY, m2 = -INFINITY, m3 = -INFINITY;
  for (int base = 0; base < deg; base += 64) {
    int idx = base + lane;
    if (idx < deg) {
      int s = csr[row + idx];
      const float4 a4 = *(const float4*)(as_ + s * 4);
      m0 = fmaxf(m0, lrelu(a4.x + ad4.x));
      m1 = fmaxf(m1, lrelu(a4.y + ad4.y));
      m2 = fmaxf(m2, lrelu(a4.z + ad4.z));
      m3 = fmaxf(m3, lrelu(a4.w + ad4.w));
    }
  }
#pragma unroll
  for (int off = 32; off; off >>= 1) {
    m0 = fmaxf(m0, __shfl_xor(m0, off));
    m1 = fmaxf(m1, __shfl_xor(m1, off));
    m2 = fmaxf(m2, __shfl_xor(m2, off));
    m3 = fmaxf(m3, __shfl_xor(m3, off));
  }

  // pass B: w = exp(e-m); z += w; acc += w * h[src, lane]
  float z0 = 0.f, z1 = 0.f, z2 = 0.f, z3 = 0.f;
  float acc = 0.f;
  for (int base = 0; base < deg; base += 64) {
    int idx = base + lane;
    int s = 0;
    float w0 = 0.f, w1 = 0.f, w2 = 0.f, w3 = 0.f;
    if (idx < deg) {
      s = csr[row + idx];
      const float4 a4 = *(const float4*)(as_ + s * 4);
      w0 = __expf(lrelu(a4.x + ad4.x) - m0);
      w1 = __expf(lrelu(a4.y + ad4.y) - m1);
      w2 = __expf(lrelu(a4.z + ad4.z) - m2);
      w3 = __expf(lrelu(a4.w + ad4.w) - m3);
    }
    z0 += w0; z1 += w1; z2 += w2; z3 += w3;
    lds_s[wv][lane] = s;
    lds_w[wv][0 * 64 + lane] = w0;
    lds_w[wv][1 * 64 + lane] = w1;
    lds_w[wv][2 * 64 + lane] = w2;
    lds_w[wv][3 * 64 + lane] = w3;
    // same-wave write->read: compiler inserts lgkmcnt wait, no barrier needed
    int cnt = min(64, deg - base);
    const int4* sp = (const int4*)&lds_s[wv][0];
    const float4* wp = (const float4*)&lds_w[wv][head * 64];
    int j = 0;
    for (; j + 4 <= cnt; j += 4) {
      int4 s4 = sp[j >> 2];
      float4 w4 = wp[j >> 2];
      float g0 = h[(size_t)s4.x * 64 + lane];
      float g1 = h[(size_t)s4.y * 64 + lane];
      float g2 = h[(size_t)s4.z * 64 + lane];
      float g3 = h[(size_t)s4.w * 64 + lane];
      acc = fmaf(w4.x, g0, acc);
      acc = fmaf(w4.y, g1, acc);
      acc = fmaf(w4.z, g2, acc);
      acc = fmaf(w4.w, g3, acc);
    }
    for (; j < cnt; ++j) {
      int sj = lds_s[wv][j];
      float wj = lds_w[wv][head * 64 + j];
      acc = fmaf(wj, h[(size_t)sj * 64 + lane], acc);
    }
  }
#pragma unroll
  for (int off = 32; off; off >>= 1) {
    z0 += __shfl_xor(z0, off);
    z1 += __shfl_xor(z1, off);
    z2 += __shfl_xor(z2, off);
    z3 += __shfl_xor(z3, off);
  }
  float zsel = head == 0 ? z0 : head == 1 ? z1 : head == 2 ? z2 : z3;
  hout[(size_t)node * 64 + lane] = acc / zsel + bias[lane];
}

// =============================== pooling ====================================

__global__ void zero_pool_kernel(float* __restrict__ pool, float* __restrict__ cnt) {
  int i = blockIdx.x * blockDim.x + threadIdx.x;
  if (i < NGRAPH * 64) pool[i] = 0.f;
  if (i < NGRAPH) cnt[i] = 0.f;
}

// 16 nodes per wave for parallelism; batch sorted -> few atomics
__global__ void pool_kernel(const float* __restrict__ h,
                            const int* __restrict__ batch,
                            float* __restrict__ pool,
                            float* __restrict__ cnt, int n_nodes) {
  int lane = threadIdx.x & 63;
  int wave = (blockIdx.x * blockDim.x + threadIdx.x) >> 6;
  int n0 = wave * 16;
  if (n0 >= n_nodes) return;
  int n1 = min(n0 + 16, n_nodes);
  int gcur = batch[n0];
  float acc = 0.f, c_acc = 0.f;
  for (int n = n0; n < n1; ++n) {
    int g = batch[n];
    if (g != gcur) {
      atomicAdd(&pool[gcur * 64 + lane], acc);
      if (lane == 0) atomicAdd(&cnt[gcur], c_acc);
      acc = 0.f; c_acc = 0.f; gcur = g;
    }
    acc += h[(size_t)n * 64 + lane];
    c_acc += 1.f;
  }
  atomicAdd(&pool[gcur * 64 + lane], acc);
  if (lane == 0) atomicAdd(&cnt[gcur], c_acc);
}

__global__ void final_kernel(const float* __restrict__ pool,
                             const float* __restrict__ cnt,
                             const float* __restrict__ Wf,
                             const float* __restrict__ bf,
                             float* __restrict__ out) {
  int g = blockIdx.x;
  int o = threadIdx.x;
  if (o >= 5) return;
  float cg = cnt[g];
  cg = cg > 1.f ? cg : 1.f;
  float acc = bf[o];
  for (int c = 0; c < 64; ++c)
    acc += (pool[g * 64 + c] / cg) * Wf[c * 5 + o];
  out[g * 5 + o] = acc;
}

extern "C" void kernel_launch(void* const* d_in, const int* in_sizes, int n_in,
                              void* d_out, int out_size, void* d_ws, size_t ws_size,
                              hipStream_t stream) {
  const float* x     = (const float*)d_in[0];
  const int*   ei    = (const int*)d_in[1];
  const int*   batch = (const int*)d_in[2];
  const float* W0    = (const float*)d_in[3];
  const float* as0   = (const float*)d_in[4];
  const float* ad0   = (const float*)d_in[5];
  const float* b0    = (const float*)d_in[6];
  const float* Wh    = (const float*)d_in[7];
  const float* ash   = (const float*)d_in[8];
  const float* adh   = (const float*)d_in[9];
  const float* bh    = (const float*)d_in[10];
  const float* Wf    = (const float*)d_in[11];
  const float* bf    = (const float*)d_in[12];
  float* out = (float*)d_out;

  const int N = in_sizes[0];       // 50000
  const int E = in_sizes[1] / 2;   // 800000
  const int* src = ei;
  const int* dst = ei + E;
  const int nE = E + N;            // with self-loops

  // workspace layout
  float* ws  = (float*)d_ws;
  float* hA  = ws;                            // N*64
  float* hB  = hA + (size_t)N * 64;           // N*64
  float* asb = hB + (size_t)N * 64;           // N*4
  float* adb = asb + (size_t)N * 4;           // N*4
  int* counts   = (int*)(adb + (size_t)N * 4);  // N
  int* offsets  = counts + N;                   // N
  int* cursor   = offsets + N;                  // N
  int* scanned  = cursor + N;                   // N
  int* blockSums = scanned + N;                 // 256
  int* csr      = blockSums + 256;              // nE
  float* pool   = (float*)(csr + nE);           // 64*64
  float* cnt    = pool + NGRAPH * 64;           // 64

  const int nodeBlocks  = (N + 255) / 256;
  const int edgeBlocks  = (E + 255) / 256;
  const int nodeWaveBlocks = (N + 3) / 4;
  const int poolWaves   = (N + 15) / 16;
  const int poolBlocks  = (poolWaves + 3) / 4;

  // ---- build CSR by dst (once; reused for all 4 layers) ----
  deg_init_kernel<<<nodeBlocks, 256, 0, stream>>>(counts, N);
  deg_count_kernel<<<edgeBlocks, 256, 0, stream>>>(dst, counts, E);
  scan1_kernel<<<nodeBlocks, 256, 0, stream>>>(counts, scanned, blockSums, N);
  scan2_kernel<<<1, 256, 0, stream>>>(blockSums, nodeBlocks);
  scan3_kernel<<<nodeBlocks, 256, 0, stream>>>(scanned, blockSums, offsets, cursor, csr, N);
  scatter_kernel<<<edgeBlocks, 256, 0, stream>>>(src, dst, cursor, csr, E);

  for (int layer = 0; layer < 4; ++layer) {
    if (layer == 0) {
      transform0_kernel<<<2048, 256, 0, stream>>>(x, W0, as0, ad0, hA, asb, adb, N);
    } else {
      transform_kernel<<<1024, 256, 0, stream>>>(hB, Wh + (size_t)(layer - 1) * 64 * 64,
                                                 ash + (layer - 1) * 64, adh + (layer - 1) * 64,
                                                 hA, asb, adb, N);
    }
    const float* bias = (layer == 0) ? b0 : (bh + (layer - 1) * 64);
    aggregate_kernel<<<nodeWaveBlocks, 256, 0, stream>>>(offsets, counts, csr,
                                                         asb, adb, hA, bias, hB, N);
  }

  zero_pool_kernel<<<(NGRAPH * 64 + 255) / 256, 256, 0, stream>>>(pool, cnt);
  pool_kernel<<<poolBlocks, 256, 0, stream>>>(hB, batch, pool, cnt, N);
  final_kernel<<<NGRAPH, 64, 0, stream>>>(pool, cnt, Wf, bf, out);
}

// Round 4
// 384.421 us; speedup vs baseline: 4.6454x; 1.1470x over previous
//
#include <hip/hip_runtime.h>
#include <cmath>

#define NEG_SLOPE 0.2f
static constexpr int NGRAPH = 64;

__device__ __forceinline__ float lrelu(float x) {
  return x > 0.f ? x : NEG_SLOPE * x;
}

// ---- layer-0 transform: h[n,c] = x[n] * W0[c] (Fin = 1), plus head dots ----
__global__ void transform0_kernel(const float* __restrict__ x,
                                  const float* __restrict__ W0,
                                  const float* __restrict__ a_src,
                                  const float* __restrict__ a_dst,
                                  float* __restrict__ h,
                                  float* __restrict__ as_,
                                  float* __restrict__ ad_,
                                  int n_nodes) {
  int lane = threadIdx.x & 63;
  int wave = (blockIdx.x * blockDim.x + threadIdx.x) >> 6;
  int nwaves = (gridDim.x * blockDim.x) >> 6;
  int head = lane >> 4, ch = lane & 15;
  float w0 = W0[lane];
  float asc = a_src[head * 16 + ch];
  float adc = a_dst[head * 16 + ch];
  for (int n = wave; n < n_nodes; n += nwaves) {
    float v = x[n] * w0;
    h[(size_t)n * 64 + lane] = v;
    float s = v * asc, d = v * adc;
#pragma unroll
    for (int off = 8; off; off >>= 1) {
      s += __shfl_down(s, off, 16);
      d += __shfl_down(d, off, 16);
    }
    if (ch == 0) { as_[n * 4 + head] = s; ad_[n * 4 + head] = d; }
  }
}

// ---- hidden-layer transform: W column in 64 VGPRs; h-row via s_load ----
__global__ void transform_kernel(const float* __restrict__ hin,
                                 const float* __restrict__ W,
                                 const float* __restrict__ a_src,
                                 const float* __restrict__ a_dst,
                                 float* __restrict__ hout,
                                 float* __restrict__ as_,
                                 float* __restrict__ ad_,
                                 int n_nodes) {
  int lane = threadIdx.x & 63;
  int wave = (blockIdx.x * blockDim.x + threadIdx.x) >> 6;
  int nwaves = (gridDim.x * blockDim.x) >> 6;
  int head = lane >> 4, ch = lane & 15;
  float wreg[64];
#pragma unroll
  for (int k = 0; k < 64; ++k) wreg[k] = W[k * 64 + lane];
  float asc = a_src[head * 16 + ch];
  float adc = a_dst[head * 16 + ch];
  for (int n = wave; n < n_nodes; n += nwaves) {
    int nu = __builtin_amdgcn_readfirstlane(n);
    const float* hrow = hin + (size_t)nu * 64;
    float acc = 0.f;
#pragma unroll
    for (int k = 0; k < 64; ++k) acc = fmaf(hrow[k], wreg[k], acc);
    hout[(size_t)nu * 64 + lane] = acc;
    float s = acc * asc, d = acc * adc;
#pragma unroll
    for (int off = 8; off; off >>= 1) {
      s += __shfl_down(s, off, 16);
      d += __shfl_down(d, off, 16);
    }
    if (ch == 0) { as_[nu * 4 + head] = s; ad_[nu * 4 + head] = d; }
  }
}

// ================= binned CSR build (nodes-per-bucket = 256) ================

__global__ void bucket_zero_kernel(int* __restrict__ bucketCounts, int nb) {
  int i = blockIdx.x * blockDim.x + threadIdx.x;
  if (i <= nb) bucketCounts[i] = 0;
}

// per-block LDS histogram over buckets, flushed with one atomic per bucket
__global__ void bucket_hist_kernel(const int* __restrict__ dst,
                                   int* __restrict__ bucketCounts,
                                   int nedge, int nb, int tile) {
  __shared__ int hist[256];
  hist[threadIdx.x] = 0;
  __syncthreads();
  int start = blockIdx.x * tile;
  int end = min(start + tile, nedge);
  for (int e = start + threadIdx.x; e < end; e += 256)
    atomicAdd(&hist[dst[e] >> 8], 1);
  __syncthreads();
  if (threadIdx.x < nb && hist[threadIdx.x])
    atomicAdd(&bucketCounts[threadIdx.x], hist[threadIdx.x]);
}

// single-block exclusive scan of bucketCounts -> bucketOffsets (+total), cursor
__global__ void bucket_scan_kernel(const int* __restrict__ bucketCounts,
                                   int* __restrict__ bucketOffsets,
                                   int* __restrict__ bucketCursor, int nb) {
  __shared__ int tmp[256];
  int tid = threadIdx.x;
  int v = (tid < nb) ? bucketCounts[tid] : 0;
  tmp[tid] = v;
  __syncthreads();
#pragma unroll
  for (int off = 1; off < 256; off <<= 1) {
    int t = (tid >= off) ? tmp[tid - off] : 0;
    __syncthreads();
    tmp[tid] += t;
    __syncthreads();
  }
  if (tid < nb) {
    int excl = tmp[tid] - v;
    bucketOffsets[tid] = excl;
    bucketCursor[tid] = excl;
  }
  if (tid == 0) bucketOffsets[nb] = tmp[255];
}

// scatter (src,dst) pairs into bucket-contiguous regions
__global__ void bucket_scatter_kernel(const int* __restrict__ src,
                                      const int* __restrict__ dst,
                                      int* __restrict__ bucketCursor,
                                      int2* __restrict__ binEdges,
                                      int nedge, int nb, int tile) {
  __shared__ int hist[256];
  __shared__ int base[256];
  hist[threadIdx.x] = 0;
  __syncthreads();
  int start = blockIdx.x * tile;
  int end = min(start + tile, nedge);
  for (int e = start + threadIdx.x; e < end; e += 256)
    atomicAdd(&hist[dst[e] >> 8], 1);
  __syncthreads();
  if (threadIdx.x < nb) {
    int c = hist[threadIdx.x];
    base[threadIdx.x] = c ? atomicAdd(&bucketCursor[threadIdx.x], c) : 0;
    hist[threadIdx.x] = 0;
  }
  __syncthreads();
  for (int e = start + threadIdx.x; e < end; e += 256) {
    int b = dst[e] >> 8;
    int r = atomicAdd(&hist[b], 1);
    binEdges[base[b] + r] = make_int2(src[e], dst[e]);
  }
}

// one block per bucket: LDS hist -> scan -> offsets/counts/self -> scatter csr
__global__ void csr_build_kernel(const int2* __restrict__ binEdges,
                                 const int* __restrict__ bucketOffsets,
                                 int* __restrict__ offsets,
                                 int* __restrict__ counts,
                                 int* __restrict__ csr, int n_nodes) {
  __shared__ int hist[256];
  __shared__ int tmp[256];
  int tid = threadIdx.x;
  int b = blockIdx.x;
  int n0 = b << 8;
  int nLoc = min(256, n_nodes - n0);
  int eBase = bucketOffsets[b];
  int cntE = bucketOffsets[b + 1] - eBase;
  hist[tid] = 0;
  __syncthreads();
  for (int i = tid; i < cntE; i += 256)
    atomicAdd(&hist[binEdges[eBase + i].y - n0], 1);
  __syncthreads();
  int v = (tid < nLoc) ? hist[tid] + 1 : 0;  // +1 = self-loop
  tmp[tid] = v;
  __syncthreads();
#pragma unroll
  for (int off = 1; off < 256; off <<= 1) {
    int t = (tid >= off) ? tmp[tid - off] : 0;
    __syncthreads();
    tmp[tid] += t;
    __syncthreads();
  }
  int excl = tmp[tid] - v;
  __syncthreads();
  if (tid < nLoc) {
    int rowStart = eBase + n0 + excl;
    offsets[n0 + tid] = rowStart;
    counts[n0 + tid] = v;
    csr[rowStart] = n0 + tid;  // self edge in slot 0
    hist[tid] = excl + 1;      // local cursor
  }
  __syncthreads();
  for (int i = tid; i < cntE; i += 256) {
    int2 e = binEdges[eBase + i];
    int l = e.y - n0;
    int r = atomicAdd(&hist[l], 1);
    csr[eBase + n0 + r] = e.x;
  }
}

// ========== fused segment max + softmax + weighted gather, wave/node ========
// Fast path (deg<=64): one pass, float4 gather (4 edges / VMEM instr).
__global__ void aggregate_kernel(const int* __restrict__ offsets,
                                 const int* __restrict__ counts,
                                 const int* __restrict__ csr,
                                 const float* __restrict__ as_,
                                 const float* __restrict__ ad_,
                                 const float* __restrict__ h,
                                 const float* __restrict__ bias,
                                 float* __restrict__ hout, int n_nodes) {
  __shared__ int lds_s[4][64];
  __shared__ float lds_w[4][4 * 68];  // stride 68: conflict-free read pattern
  int lane = threadIdx.x & 63;
  int wv = threadIdx.x >> 6;
  int node = (blockIdx.x * blockDim.x + threadIdx.x) >> 6;
  if (node >= n_nodes) return;
  int row = offsets[node];
  int deg = counts[node];
  const float4 ad4 = *(const float4*)(ad_ + node * 4);

  if (deg <= 64) {
    // --- fused single pass ---
    bool valid = lane < deg;
    int s = 0;
    float e0 = -INFINITY, e1 = -INFINITY, e2 = -INFINITY, e3 = -INFINITY;
    if (valid) {
      s = csr[row + lane];
      const float4 a4 = *(const float4*)(as_ + s * 4);
      e0 = lrelu(a4.x + ad4.x);
      e1 = lrelu(a4.y + ad4.y);
      e2 = lrelu(a4.z + ad4.z);
      e3 = lrelu(a4.w + ad4.w);
    }
    float m0 = e0, m1 = e1, m2 = e2, m3 = e3;
#pragma unroll
    for (int off = 32; off; off >>= 1) {
      m0 = fmaxf(m0, __shfl_xor(m0, off));
      m1 = fmaxf(m1, __shfl_xor(m1, off));
      m2 = fmaxf(m2, __shfl_xor(m2, off));
      m3 = fmaxf(m3, __shfl_xor(m3, off));
    }
    float w0 = 0.f, w1 = 0.f, w2 = 0.f, w3 = 0.f;
    if (valid) {
      w0 = __expf(e0 - m0);
      w1 = __expf(e1 - m1);
      w2 = __expf(e2 - m2);
      w3 = __expf(e3 - m3);
    }
    lds_s[wv][lane] = valid ? s : 0;
    lds_w[wv][0 * 68 + lane] = w0;
    lds_w[wv][1 * 68 + lane] = w1;
    lds_w[wv][2 * 68 + lane] = w2;
    lds_w[wv][3 * 68 + lane] = w3;
    // lanes re-split 16x4: lane handles channels chBase..chBase+3 of edge grp
    int grp = lane >> 4;
    int chBase = (lane & 15) * 4;
    int headL = (lane & 15) >> 2;
    float ax = 0.f, ay = 0.f, az = 0.f, aw = 0.f, zacc = 0.f;
    int iters = (deg + 3) >> 2;
    for (int it = 0; it < iters; ++it) {
      int j = it * 4 + grp;
      int sj = lds_s[wv][j];
      float wj = lds_w[wv][headL * 68 + j];
      const float4 g = *(const float4*)(h + (size_t)sj * 64 + chBase);
      ax = fmaf(wj, g.x, ax);
      ay = fmaf(wj, g.y, ay);
      az = fmaf(wj, g.z, az);
      aw = fmaf(wj, g.w, aw);
      zacc += wj;
    }
    // combine the 4 edge-groups (lanes L, L^16, L^32, L^48)
    ax += __shfl_xor(ax, 16); ax += __shfl_xor(ax, 32);
    ay += __shfl_xor(ay, 16); ay += __shfl_xor(ay, 32);
    az += __shfl_xor(az, 16); az += __shfl_xor(az, 32);
    aw += __shfl_xor(aw, 16); aw += __shfl_xor(aw, 32);
    zacc += __shfl_xor(zacc, 16); zacc += __shfl_xor(zacc, 32);
    if (lane < 16) {
      const float4 b4 = *(const float4*)(bias + chBase);
      float4 o;
      o.x = ax / zacc + b4.x;
      o.y = ay / zacc + b4.y;
      o.z = az / zacc + b4.z;
      o.w = aw / zacc + b4.w;
      *(float4*)(hout + (size_t)node * 64 + chBase) = o;
    }
    return;
  }

  // --- slow path (deg > 64): two-pass, scalar gather (rare) ---
  int head = lane >> 4;
  float m0 = -INFINITY, m1 = -INFINITY, m2 = -INFINITY, m3 = -INFINITY;
  for (int base = 0; base < deg; base += 64) {
    int idx = base + lane;
    if (idx < deg) {
      int s = csr[row + idx];
      const float4 a4 = *(const float4*)(as_ + s * 4);
      m0 = fmaxf(m0, lrelu(a4.x + ad4.x));
      m1 = fmaxf(m1, lrelu(a4.y + ad4.y));
      m2 = fmaxf(m2, lrelu(a4.z + ad4.z));
      m3 = fmaxf(m3, lrelu(a4.w + ad4.w));
    }
  }
#pragma unroll
  for (int off = 32; off; off >>= 1) {
    m0 = fmaxf(m0, __shfl_xor(m0, off));
    m1 = fmaxf(m1, __shfl_xor(m1, off));
    m2 = fmaxf(m2, __shfl_xor(m2, off));
    m3 = fmaxf(m3, __shfl_xor(m3, off));
  }
  float z0 = 0.f, z1 = 0.f, z2 = 0.f, z3 = 0.f;
  float acc = 0.f;
  for (int base = 0; base < deg; base += 64) {
    int idx = base + lane;
    int s = 0;
    float w0 = 0.f, w1 = 0.f, w2 = 0.f, w3 = 0.f;
    if (idx < deg) {
      s = csr[row + idx];
      const float4 a4 = *(const float4*)(as_ + s * 4);
      w0 = __expf(lrelu(a4.x + ad4.x) - m0);
      w1 = __expf(lrelu(a4.y + ad4.y) - m1);
      w2 = __expf(lrelu(a4.z + ad4.z) - m2);
      w3 = __expf(lrelu(a4.w + ad4.w) - m3);
    }
    z0 += w0; z1 += w1; z2 += w2; z3 += w3;
    lds_s[wv][lane] = s;
    lds_w[wv][0 * 68 + lane] = w0;
    lds_w[wv][1 * 68 + lane] = w1;
    lds_w[wv][2 * 68 + lane] = w2;
    lds_w[wv][3 * 68 + lane] = w3;
    int cnt = min(64, deg - base);
    for (int j = 0; j < cnt; ++j) {
      int sj = lds_s[wv][j];
      float wj = lds_w[wv][head * 68 + j];
      acc = fmaf(wj, h[(size_t)sj * 64 + lane], acc);
    }
  }
#pragma unroll
  for (int off = 32; off; off >>= 1) {
    z0 += __shfl_xor(z0, off);
    z1 += __shfl_xor(z1, off);
    z2 += __shfl_xor(z2, off);
    z3 += __shfl_xor(z3, off);
  }
  float zsel = head == 0 ? z0 : head == 1 ? z1 : head == 2 ? z2 : z3;
  hout[(size_t)node * 64 + lane] = acc / zsel + bias[lane];
}

// =============================== pooling ====================================

__global__ void zero_pool_kernel(float* __restrict__ pool, float* __restrict__ cnt) {
  int i = blockIdx.x * blockDim.x + threadIdx.x;
  if (i < NGRAPH * 64) pool[i] = 0.f;
  if (i < NGRAPH) cnt[i] = 0.f;
}

__global__ void pool_kernel(const float* __restrict__ h,
                            const int* __restrict__ batch,
                            float* __restrict__ pool,
                            float* __restrict__ cnt, int n_nodes) {
  int lane = threadIdx.x & 63;
  int wave = (blockIdx.x * blockDim.x + threadIdx.x) >> 6;
  int n0 = wave * 16;
  if (n0 >= n_nodes) return;
  int n1 = min(n0 + 16, n_nodes);
  int gcur = batch[n0];
  float acc = 0.f, c_acc = 0.f;
  for (int n = n0; n < n1; ++n) {
    int g = batch[n];
    if (g != gcur) {
      atomicAdd(&pool[gcur * 64 + lane], acc);
      if (lane == 0) atomicAdd(&cnt[gcur], c_acc);
      acc = 0.f; c_acc = 0.f; gcur = g;
    }
    acc += h[(size_t)n * 64 + lane];
    c_acc += 1.f;
  }
  atomicAdd(&pool[gcur * 64 + lane], acc);
  if (lane == 0) atomicAdd(&cnt[gcur], c_acc);
}

__global__ void final_kernel(const float* __restrict__ pool,
                             const float* __restrict__ cnt,
                             const float* __restrict__ Wf,
                             const float* __restrict__ bf,
                             float* __restrict__ out) {
  int g = blockIdx.x;
  int o = threadIdx.x;
  if (o >= 5) return;
  float cg = cnt[g];
  cg = cg > 1.f ? cg : 1.f;
  float acc = bf[o];
  for (int c = 0; c < 64; ++c)
    acc += (pool[g * 64 + c] / cg) * Wf[c * 5 + o];
  out[g * 5 + o] = acc;
}

extern "C" void kernel_launch(void* const* d_in, const int* in_sizes, int n_in,
                              void* d_out, int out_size, void* d_ws, size_t ws_size,
                              hipStream_t stream) {
  const float* x     = (const float*)d_in[0];
  const int*   ei    = (const int*)d_in[1];
  const int*   batch = (const int*)d_in[2];
  const float* W0    = (const float*)d_in[3];
  const float* as0   = (const float*)d_in[4];
  const float* ad0   = (const float*)d_in[5];
  const float* b0    = (const float*)d_in[6];
  const float* Wh    = (const float*)d_in[7];
  const float* ash   = (const float*)d_in[8];
  const float* adh   = (const float*)d_in[9];
  const float* bh    = (const float*)d_in[10];
  const float* Wf    = (const float*)d_in[11];
  const float* bf    = (const float*)d_in[12];
  float* out = (float*)d_out;

  const int N = in_sizes[0];       // 50000
  const int E = in_sizes[1] / 2;   // 800000
  const int* src = ei;
  const int* dst = ei + E;
  const int nE = E + N;
  const int NB = (N + 255) >> 8;   // buckets of 256 nodes (196)

  // workspace layout
  float* ws  = (float*)d_ws;
  float* hA  = ws;                              // N*64
  float* hB  = hA + (size_t)N * 64;             // N*64
  float* asb = hB + (size_t)N * 64;             // N*4
  float* adb = asb + (size_t)N * 4;             // N*4
  int* counts  = (int*)(adb + (size_t)N * 4);   // N
  int* offsets = counts + N;                    // N
  int* csr     = offsets + N;                   // nE
  float* pool  = (float*)(csr + nE);            // 64*64
  float* cnt   = pool + NGRAPH * 64;            // 64
  int* bucketCounts  = (int*)(cnt + NGRAPH);    // NB+1
  int* bucketOffsets = bucketCounts + NB + 1;   // NB+1
  int* bucketCursor  = bucketOffsets + NB + 1;  // NB
  // binEdges aliases hA: only live during CSR build, before any transform.
  int2* binEdges = (int2*)hA;                   // E pairs (6.4 MB <= 12.8 MB)

  const int TILE = 2048;
  const int binBlocks = (E + TILE - 1) / TILE;
  const int nodeWaveBlocks = (N + 3) / 4;
  const int poolWaves = (N + 15) / 16;
  const int poolBlocks = (poolWaves + 3) / 4;

  // ---- binned CSR build (once; reused for all 4 layers) ----
  bucket_zero_kernel<<<1, 256, 0, stream>>>(bucketCounts, NB);
  bucket_hist_kernel<<<binBlocks, 256, 0, stream>>>(dst, bucketCounts, E, NB, TILE);
  bucket_scan_kernel<<<1, 256, 0, stream>>>(bucketCounts, bucketOffsets, bucketCursor, NB);
  bucket_scatter_kernel<<<binBlocks, 256, 0, stream>>>(src, dst, bucketCursor, binEdges, E, NB, TILE);
  csr_build_kernel<<<NB, 256, 0, stream>>>(binEdges, bucketOffsets, offsets, counts, csr, N);

  for (int layer = 0; layer < 4; ++layer) {
    if (layer == 0) {
      transform0_kernel<<<2048, 256, 0, stream>>>(x, W0, as0, ad0, hA, asb, adb, N);
    } else {
      transform_kernel<<<1024, 256, 0, stream>>>(hB, Wh + (size_t)(layer - 1) * 64 * 64,
                                                 ash + (layer - 1) * 64, adh + (layer - 1) * 64,
                                                 hA, asb, adb, N);
    }
    const float* bias = (layer == 0) ? b0 : (bh + (layer - 1) * 64);
    aggregate_kernel<<<nodeWaveBlocks, 256, 0, stream>>>(offsets, counts, csr,
                                                         asb, adb, hA, bias, hB, N);
  }

  zero_pool_kernel<<<(NGRAPH * 64 + 255) / 256, 256, 0, stream>>>(pool, cnt);
  pool_kernel<<<poolBlocks, 256, 0, stream>>>(hB, batch, pool, cnt, N);
  final_kernel<<<NGRAPH, 64, 0, stream>>>(pool, cnt, Wf, bf, out);
}

// Round 5
// 350.899 us; speedup vs baseline: 5.0891x; 1.0955x over previous
//
#include <hip/hip_runtime.h>
#include <cmath>

#define NEG_SLOPE 0.2f
static constexpr int NGRAPH = 64;

__device__ __forceinline__ float lrelu(float x) {
  return x > 0.f ? x : NEG_SLOPE * x;
}

// ---- layer-0 transform: h[n,c] = x[n] * W0[c] (Fin = 1), plus head dots ----
__global__ void transform0_kernel(const float* __restrict__ x,
                                  const float* __restrict__ W0,
                                  const float* __restrict__ a_src,
                                  const float* __restrict__ a_dst,
                                  float* __restrict__ h,
                                  float* __restrict__ as_,
                                  float* __restrict__ ad_,
                                  int n_nodes) {
  int lane = threadIdx.x & 63;
  int wave = (blockIdx.x * blockDim.x + threadIdx.x) >> 6;
  int nwaves = (gridDim.x * blockDim.x) >> 6;
  int head = lane >> 4, ch = lane & 15;
  float w0 = W0[lane];
  float asc = a_src[head * 16 + ch];
  float adc = a_dst[head * 16 + ch];
  for (int n = wave; n < n_nodes; n += nwaves) {
    float v = x[n] * w0;
    h[(size_t)n * 64 + lane] = v;
    float s = v * asc, d = v * adc;
#pragma unroll
    for (int off = 8; off; off >>= 1) {
      s += __shfl_down(s, off, 16);
      d += __shfl_down(d, off, 16);
    }
    if (ch == 0) { as_[n * 4 + head] = s; ad_[n * 4 + head] = d; }
  }
}

// ---- hidden-layer transform: W column in 64 VGPRs; h-row via s_load ----
__global__ void transform_kernel(const float* __restrict__ hin,
                                 const float* __restrict__ W,
                                 const float* __restrict__ a_src,
                                 const float* __restrict__ a_dst,
                                 float* __restrict__ hout,
                                 float* __restrict__ as_,
                                 float* __restrict__ ad_,
                                 int n_nodes) {
  int lane = threadIdx.x & 63;
  int wave = (blockIdx.x * blockDim.x + threadIdx.x) >> 6;
  int nwaves = (gridDim.x * blockDim.x) >> 6;
  int head = lane >> 4, ch = lane & 15;
  float wreg[64];
#pragma unroll
  for (int k = 0; k < 64; ++k) wreg[k] = W[k * 64 + lane];
  float asc = a_src[head * 16 + ch];
  float adc = a_dst[head * 16 + ch];
  for (int n = wave; n < n_nodes; n += nwaves) {
    int nu = __builtin_amdgcn_readfirstlane(n);
    const float* hrow = hin + (size_t)nu * 64;
    float acc = 0.f;
#pragma unroll
    for (int k = 0; k < 64; ++k) acc = fmaf(hrow[k], wreg[k], acc);
    hout[(size_t)nu * 64 + lane] = acc;
    float s = acc * asc, d = acc * adc;
#pragma unroll
    for (int off = 8; off; off >>= 1) {
      s += __shfl_down(s, off, 16);
      d += __shfl_down(d, off, 16);
    }
    if (ch == 0) { as_[nu * 4 + head] = s; ad_[nu * 4 + head] = d; }
  }
}

// ================= binned CSR build (nodes-per-bucket = 256) ================

// also zeroes the pool accumulators (used much later; safe to init here)
__global__ void init_kernel(int* __restrict__ bucketCounts, int nb,
                            float* __restrict__ pool, float* __restrict__ cnt) {
  int i = blockIdx.x * blockDim.x + threadIdx.x;
  if (i <= nb) bucketCounts[i] = 0;
  if (i < NGRAPH * 64) pool[i] = 0.f;
  if (i < NGRAPH) cnt[i] = 0.f;
}

__global__ void bucket_hist_kernel(const int* __restrict__ dst,
                                   int* __restrict__ bucketCounts,
                                   int nedge, int nb, int tile) {
  __shared__ int hist[256];
  hist[threadIdx.x] = 0;
  __syncthreads();
  int start = blockIdx.x * tile;
  int end = min(start + tile, nedge);
  for (int e = start + threadIdx.x; e < end; e += 256)
    atomicAdd(&hist[dst[e] >> 8], 1);
  __syncthreads();
  if (threadIdx.x < nb && hist[threadIdx.x])
    atomicAdd(&bucketCounts[threadIdx.x], hist[threadIdx.x]);
}

__global__ void bucket_scan_kernel(const int* __restrict__ bucketCounts,
                                   int* __restrict__ bucketOffsets,
                                   int* __restrict__ bucketCursor, int nb) {
  __shared__ int tmp[256];
  int tid = threadIdx.x;
  int v = (tid < nb) ? bucketCounts[tid] : 0;
  tmp[tid] = v;
  __syncthreads();
#pragma unroll
  for (int off = 1; off < 256; off <<= 1) {
    int t = (tid >= off) ? tmp[tid - off] : 0;
    __syncthreads();
    tmp[tid] += t;
    __syncthreads();
  }
  if (tid < nb) {
    int excl = tmp[tid] - v;
    bucketOffsets[tid] = excl;
    bucketCursor[tid] = excl;
  }
  if (tid == 0) bucketOffsets[nb] = tmp[255];
}

__global__ void bucket_scatter_kernel(const int* __restrict__ src,
                                      const int* __restrict__ dst,
                                      int* __restrict__ bucketCursor,
                                      int2* __restrict__ binEdges,
                                      int nedge, int nb, int tile) {
  __shared__ int hist[256];
  __shared__ int base[256];
  hist[threadIdx.x] = 0;
  __syncthreads();
  int start = blockIdx.x * tile;
  int end = min(start + tile, nedge);
  for (int e = start + threadIdx.x; e < end; e += 256)
    atomicAdd(&hist[dst[e] >> 8], 1);
  __syncthreads();
  if (threadIdx.x < nb) {
    int c = hist[threadIdx.x];
    base[threadIdx.x] = c ? atomicAdd(&bucketCursor[threadIdx.x], c) : 0;
    hist[threadIdx.x] = 0;
  }
  __syncthreads();
  for (int e = start + threadIdx.x; e < end; e += 256) {
    int b = dst[e] >> 8;
    int r = atomicAdd(&hist[b], 1);
    binEdges[base[b] + r] = make_int2(src[e], dst[e]);
  }
}

__global__ void csr_build_kernel(const int2* __restrict__ binEdges,
                                 const int* __restrict__ bucketOffsets,
                                 int* __restrict__ offsets,
                                 int* __restrict__ counts,
                                 int* __restrict__ csr, int n_nodes) {
  __shared__ int hist[256];
  __shared__ int tmp[256];
  int tid = threadIdx.x;
  int b = blockIdx.x;
  int n0 = b << 8;
  int nLoc = min(256, n_nodes - n0);
  int eBase = bucketOffsets[b];
  int cntE = bucketOffsets[b + 1] - eBase;
  hist[tid] = 0;
  __syncthreads();
  for (int i = tid; i < cntE; i += 256)
    atomicAdd(&hist[binEdges[eBase + i].y - n0], 1);
  __syncthreads();
  int v = (tid < nLoc) ? hist[tid] + 1 : 0;  // +1 = self-loop
  tmp[tid] = v;
  __syncthreads();
#pragma unroll
  for (int off = 1; off < 256; off <<= 1) {
    int t = (tid >= off) ? tmp[tid - off] : 0;
    __syncthreads();
    tmp[tid] += t;
    __syncthreads();
  }
  int excl = tmp[tid] - v;
  __syncthreads();
  if (tid < nLoc) {
    int rowStart = eBase + n0 + excl;
    offsets[n0 + tid] = rowStart;
    counts[n0 + tid] = v;
    csr[rowStart] = n0 + tid;  // self edge in slot 0
    hist[tid] = excl + 1;      // local cursor
  }
  __syncthreads();
  for (int i = tid; i < cntE; i += 256) {
    int2 e = binEdges[eBase + i];
    int l = e.y - n0;
    int r = atomicAdd(&hist[l], 1);
    csr[eBase + n0 + r] = e.x;
  }
}

// ========== fused softmax + weighted gather, wave-per-node ==================
// Fast path (deg<=64): softmax max-subtraction dropped (cancels exactly in
// exact math; fp32 delta ~1e-6 << 1.9e-5 threshold; e bounded, no overflow).
// Gather loop chunked x4 so 4 float4 gathers are in flight per lane.
__global__ void aggregate_kernel(const int* __restrict__ offsets,
                                 const int* __restrict__ counts,
                                 const int* __restrict__ csr,
                                 const float* __restrict__ as_,
                                 const float* __restrict__ ad_,
                                 const float* __restrict__ h,
                                 const float* __restrict__ bias,
                                 float* __restrict__ hout, int n_nodes) {
  __shared__ int lds_s[4][64];
  __shared__ float lds_w[4][4 * 68];  // stride 68: conflict-free read pattern
  int lane = threadIdx.x & 63;
  int wv = threadIdx.x >> 6;
  int node = (blockIdx.x * blockDim.x + threadIdx.x) >> 6;
  if (node >= n_nodes) return;
  int row = offsets[node];
  int deg = counts[node];
  const float4 ad4 = *(const float4*)(ad_ + node * 4);

  if (deg <= 64) {
    bool valid = lane < deg;
    int s = 0;
    float w0 = 0.f, w1 = 0.f, w2 = 0.f, w3 = 0.f;
    if (valid) {
      s = csr[row + lane];
      const float4 a4 = *(const float4*)(as_ + s * 4);
      w0 = __expf(lrelu(a4.x + ad4.x));
      w1 = __expf(lrelu(a4.y + ad4.y));
      w2 = __expf(lrelu(a4.z + ad4.z));
      w3 = __expf(lrelu(a4.w + ad4.w));
    }
    lds_s[wv][lane] = s;
    lds_w[wv][0 * 68 + lane] = w0;
    lds_w[wv][1 * 68 + lane] = w1;
    lds_w[wv][2 * 68 + lane] = w2;
    lds_w[wv][3 * 68 + lane] = w3;
    // lanes re-split 16x4: lane handles channels chBase..+3 of edge group grp
    int grp = lane >> 4;
    int chBase = (lane & 15) * 4;
    int headL = (lane & 15) >> 2;
    float ax = 0.f, ay = 0.f, az = 0.f, aw = 0.f, zacc = 0.f;
    int iters = (deg + 3) >> 2;  // <= 16
    for (int base = 0; base < iters; base += 4) {
#pragma unroll
      for (int k = 0; k < 4; ++k) {
        int it = base + k;
        int j = (it * 4 + grp) & 63;
        int sj = lds_s[wv][j];
        float wj = (it < iters) ? lds_w[wv][headL * 68 + j] : 0.f;
        const float4 g = *(const float4*)(h + (size_t)sj * 64 + chBase);
        ax = fmaf(wj, g.x, ax);
        ay = fmaf(wj, g.y, ay);
        az = fmaf(wj, g.z, az);
        aw = fmaf(wj, g.w, aw);
        zacc += wj;
      }
    }
    // combine the 4 edge-groups (lanes L, L^16, L^32, L^48)
    ax += __shfl_xor(ax, 16); ax += __shfl_xor(ax, 32);
    ay += __shfl_xor(ay, 16); ay += __shfl_xor(ay, 32);
    az += __shfl_xor(az, 16); az += __shfl_xor(az, 32);
    aw += __shfl_xor(aw, 16); aw += __shfl_xor(aw, 32);
    zacc += __shfl_xor(zacc, 16); zacc += __shfl_xor(zacc, 32);
    if (lane < 16) {
      const float4 b4 = *(const float4*)(bias + chBase);
      float4 o;
      o.x = ax / zacc + b4.x;
      o.y = ay / zacc + b4.y;
      o.z = az / zacc + b4.z;
      o.w = aw / zacc + b4.w;
      *(float4*)(hout + (size_t)node * 64 + chBase) = o;
    }
    return;
  }

  // --- slow path (deg > 64): two-pass with max, scalar gather (rare) ---
  int head = lane >> 4;
  float m0 = -INFINITY, m1 = -INFINITY, m2 = -INFINITY, m3 = -INFINITY;
  for (int base = 0; base < deg; base += 64) {
    int idx = base + lane;
    if (idx < deg) {
      int s = csr[row + idx];
      const float4 a4 = *(const float4*)(as_ + s * 4);
      m0 = fmaxf(m0, lrelu(a4.x + ad4.x));
      m1 = fmaxf(m1, lrelu(a4.y + ad4.y));
      m2 = fmaxf(m2, lrelu(a4.z + ad4.z));
      m3 = fmaxf(m3, lrelu(a4.w + ad4.w));
    }
  }
#pragma unroll
  for (int off = 32; off; off >>= 1) {
    m0 = fmaxf(m0, __shfl_xor(m0, off));
    m1 = fmaxf(m1, __shfl_xor(m1, off));
    m2 = fmaxf(m2, __shfl_xor(m2, off));
    m3 = fmaxf(m3, __shfl_xor(m3, off));
  }
  float z0 = 0.f, z1 = 0.f, z2 = 0.f, z3 = 0.f;
  float acc = 0.f;
  for (int base = 0; base < deg; base += 64) {
    int idx = base + lane;
    int s = 0;
    float w0 = 0.f, w1 = 0.f, w2 = 0.f, w3 = 0.f;
    if (idx < deg) {
      s = csr[row + idx];
      const float4 a4 = *(const float4*)(as_ + s * 4);
      w0 = __expf(lrelu(a4.x + ad4.x) - m0);
      w1 = __expf(lrelu(a4.y + ad4.y) - m1);
      w2 = __expf(lrelu(a4.z + ad4.z) - m2);
      w3 = __expf(lrelu(a4.w + ad4.w) - m3);
    }
    z0 += w0; z1 += w1; z2 += w2; z3 += w3;
    lds_s[wv][lane] = s;
    lds_w[wv][0 * 68 + lane] = w0;
    lds_w[wv][1 * 68 + lane] = w1;
    lds_w[wv][2 * 68 + lane] = w2;
    lds_w[wv][3 * 68 + lane] = w3;
    int cnt = min(64, deg - base);
    for (int j = 0; j < cnt; ++j) {
      int sj = lds_s[wv][j];
      float wj = lds_w[wv][head * 68 + j];
      acc = fmaf(wj, h[(size_t)sj * 64 + lane], acc);
    }
  }
#pragma unroll
  for (int off = 32; off; off >>= 1) {
    z0 += __shfl_xor(z0, off);
    z1 += __shfl_xor(z1, off);
    z2 += __shfl_xor(z2, off);
    z3 += __shfl_xor(z3, off);
  }
  float zsel = head == 0 ? z0 : head == 1 ? z1 : head == 2 ? z2 : z3;
  hout[(size_t)node * 64 + lane] = acc / zsel + bias[lane];
}

// =============================== pooling ====================================

__global__ void pool_kernel(const float* __restrict__ h,
                            const int* __restrict__ batch,
                            float* __restrict__ pool,
                            float* __restrict__ cnt, int n_nodes) {
  int lane = threadIdx.x & 63;
  int wave = (blockIdx.x * blockDim.x + threadIdx.x) >> 6;
  int n0 = wave * 16;
  if (n0 >= n_nodes) return;
  int n1 = min(n0 + 16, n_nodes);
  int gcur = batch[n0];
  float acc = 0.f, c_acc = 0.f;
  for (int n = n0; n < n1; ++n) {
    int g = batch[n];
    if (g != gcur) {
      atomicAdd(&pool[gcur * 64 + lane], acc);
      if (lane == 0) atomicAdd(&cnt[gcur], c_acc);
      acc = 0.f; c_acc = 0.f; gcur = g;
    }
    acc += h[(size_t)n * 64 + lane];
    c_acc += 1.f;
  }
  atomicAdd(&pool[gcur * 64 + lane], acc);
  if (lane == 0) atomicAdd(&cnt[gcur], c_acc);
}

__global__ void final_kernel(const float* __restrict__ pool,
                             const float* __restrict__ cnt,
                             const float* __restrict__ Wf,
                             const float* __restrict__ bf,
                             float* __restrict__ out) {
  int g = blockIdx.x;
  int o = threadIdx.x;
  if (o >= 5) return;
  float cg = cnt[g];
  cg = cg > 1.f ? cg : 1.f;
  float acc = bf[o];
  for (int c = 0; c < 64; ++c)
    acc += (pool[g * 64 + c] / cg) * Wf[c * 5 + o];
  out[g * 5 + o] = acc;
}

extern "C" void kernel_launch(void* const* d_in, const int* in_sizes, int n_in,
                              void* d_out, int out_size, void* d_ws, size_t ws_size,
                              hipStream_t stream) {
  const float* x     = (const float*)d_in[0];
  const int*   ei    = (const int*)d_in[1];
  const int*   batch = (const int*)d_in[2];
  const float* W0    = (const float*)d_in[3];
  const float* as0   = (const float*)d_in[4];
  const float* ad0   = (const float*)d_in[5];
  const float* b0    = (const float*)d_in[6];
  const float* Wh    = (const float*)d_in[7];
  const float* ash   = (const float*)d_in[8];
  const float* adh   = (const float*)d_in[9];
  const float* bh    = (const float*)d_in[10];
  const float* Wf    = (const float*)d_in[11];
  const float* bf    = (const float*)d_in[12];
  float* out = (float*)d_out;

  const int N = in_sizes[0];       // 50000
  const int E = in_sizes[1] / 2;   // 800000
  const int* src = ei;
  const int* dst = ei + E;
  const int nE = E + N;
  const int NB = (N + 255) >> 8;   // buckets of 256 nodes (196)

  // workspace layout
  float* ws  = (float*)d_ws;
  float* hA  = ws;                              // N*64
  float* hB  = hA + (size_t)N * 64;             // N*64
  float* asb = hB + (size_t)N * 64;             // N*4
  float* adb = asb + (size_t)N * 4;             // N*4
  int* counts  = (int*)(adb + (size_t)N * 4);   // N
  int* offsets = counts + N;                    // N
  int* csr     = offsets + N;                   // nE
  float* pool  = (float*)(csr + nE);            // 64*64
  float* cnt   = pool + NGRAPH * 64;            // 64
  int* bucketCounts  = (int*)(cnt + NGRAPH);    // NB+1
  int* bucketOffsets = bucketCounts + NB + 1;   // NB+1
  int* bucketCursor  = bucketOffsets + NB + 1;  // NB
  // binEdges aliases hA: only live during CSR build, before any transform.
  int2* binEdges = (int2*)hA;                   // E pairs (6.4 MB <= 12.8 MB)

  const int TILE = 2048;
  const int binBlocks = (E + TILE - 1) / TILE;
  const int nodeWaveBlocks = (N + 3) / 4;
  const int poolWaves = (N + 15) / 16;
  const int poolBlocks = (poolWaves + 3) / 4;

  // ---- binned CSR build (once; reused for all 4 layers) ----
  init_kernel<<<(NGRAPH * 64 + 255) / 256, 256, 0, stream>>>(bucketCounts, NB, pool, cnt);
  bucket_hist_kernel<<<binBlocks, 256, 0, stream>>>(dst, bucketCounts, E, NB, TILE);
  bucket_scan_kernel<<<1, 256, 0, stream>>>(bucketCounts, bucketOffsets, bucketCursor, NB);
  bucket_scatter_kernel<<<binBlocks, 256, 0, stream>>>(src, dst, bucketCursor, binEdges, E, NB, TILE);
  csr_build_kernel<<<NB, 256, 0, stream>>>(binEdges, bucketOffsets, offsets, counts, csr, N);

  for (int layer = 0; layer < 4; ++layer) {
    if (layer == 0) {
      transform0_kernel<<<2048, 256, 0, stream>>>(x, W0, as0, ad0, hA, asb, adb, N);
    } else {
      transform_kernel<<<2048, 256, 0, stream>>>(hB, Wh + (size_t)(layer - 1) * 64 * 64,
                                                 ash + (layer - 1) * 64, adh + (layer - 1) * 64,
                                                 hA, asb, adb, N);
    }
    const float* bias = (layer == 0) ? b0 : (bh + (layer - 1) * 64);
    aggregate_kernel<<<nodeWaveBlocks, 256, 0, stream>>>(offsets, counts, csr,
                                                         asb, adb, hA, bias, hB, N);
  }

  pool_kernel<<<poolBlocks, 256, 0, stream>>>(hB, batch, pool, cnt, N);
  final_kernel<<<NGRAPH, 64, 0, stream>>>(pool, cnt, Wf, bf, out);
}

// Round 6
// 347.865 us; speedup vs baseline: 5.1335x; 1.0087x over previous
//
#include <hip/hip_runtime.h>
#include <cmath>

#define NEG_SLOPE 0.2f
static constexpr int NGRAPH = 64;

__device__ __forceinline__ float lrelu(float x) {
  return x > 0.f ? x : NEG_SLOPE * x;
}

// ---- fused: zero bucketCounts/pool/cnt + layer-0 transform (Fin = 1) ----
__global__ void init_transform0_kernel(const float* __restrict__ x,
                                       const float* __restrict__ W0,
                                       const float* __restrict__ a_src,
                                       const float* __restrict__ a_dst,
                                       float* __restrict__ h,
                                       float* __restrict__ as_,
                                       float* __restrict__ ad_,
                                       int n_nodes,
                                       int* __restrict__ bucketCounts, int nb,
                                       float* __restrict__ pool,
                                       float* __restrict__ cnt) {
  int gid = blockIdx.x * blockDim.x + threadIdx.x;
  if (gid <= nb) bucketCounts[gid] = 0;
  if (gid < NGRAPH * 64) pool[gid] = 0.f;
  if (gid < NGRAPH) cnt[gid] = 0.f;

  int lane = threadIdx.x & 63;
  int wave = gid >> 6;
  int nwaves = (gridDim.x * blockDim.x) >> 6;
  int head = lane >> 4, ch = lane & 15;
  float w0 = W0[lane];
  float asc = a_src[head * 16 + ch];
  float adc = a_dst[head * 16 + ch];
  for (int n = wave; n < n_nodes; n += nwaves) {
    float v = x[n] * w0;
    h[(size_t)n * 64 + lane] = v;
    float s = v * asc, d = v * adc;
#pragma unroll
    for (int off = 8; off; off >>= 1) {
      s += __shfl_down(s, off, 16);
      d += __shfl_down(d, off, 16);
    }
    if (ch == 0) { as_[n * 4 + head] = s; ad_[n * 4 + head] = d; }
  }
}

// ---- hidden-layer transform: W column in 64 VGPRs; h-row via s_load ----
__global__ void transform_kernel(const float* __restrict__ hin,
                                 const float* __restrict__ W,
                                 const float* __restrict__ a_src,
                                 const float* __restrict__ a_dst,
                                 float* __restrict__ hout,
                                 float* __restrict__ as_,
                                 float* __restrict__ ad_,
                                 int n_nodes) {
  int lane = threadIdx.x & 63;
  int wave = (blockIdx.x * blockDim.x + threadIdx.x) >> 6;
  int nwaves = (gridDim.x * blockDim.x) >> 6;
  int head = lane >> 4, ch = lane & 15;
  float wreg[64];
#pragma unroll
  for (int k = 0; k < 64; ++k) wreg[k] = W[k * 64 + lane];
  float asc = a_src[head * 16 + ch];
  float adc = a_dst[head * 16 + ch];
  for (int n = wave; n < n_nodes; n += nwaves) {
    int nu = __builtin_amdgcn_readfirstlane(n);
    const float* hrow = hin + (size_t)nu * 64;
    float acc = 0.f;
#pragma unroll
    for (int k = 0; k < 64; ++k) acc = fmaf(hrow[k], wreg[k], acc);
    hout[(size_t)nu * 64 + lane] = acc;
    float s = acc * asc, d = acc * adc;
#pragma unroll
    for (int off = 8; off; off >>= 1) {
      s += __shfl_down(s, off, 16);
      d += __shfl_down(d, off, 16);
    }
    if (ch == 0) { as_[nu * 4 + head] = s; ad_[nu * 4 + head] = d; }
  }
}

// ================= binned CSR build (nodes-per-bucket = 256) ================

__global__ void bucket_hist_kernel(const int* __restrict__ dst,
                                   int* __restrict__ bucketCounts,
                                   int nedge, int nb, int tile) {
  __shared__ int hist[256];
  hist[threadIdx.x] = 0;
  __syncthreads();
  int start = blockIdx.x * tile;
  int end = min(start + tile, nedge);
  for (int e = start + threadIdx.x; e < end; e += 256)
    atomicAdd(&hist[dst[e] >> 8], 1);
  __syncthreads();
  if (threadIdx.x < nb && hist[threadIdx.x])
    atomicAdd(&bucketCounts[threadIdx.x], hist[threadIdx.x]);
}

__global__ void bucket_scan_kernel(const int* __restrict__ bucketCounts,
                                   int* __restrict__ bucketOffsets,
                                   int* __restrict__ bucketCursor, int nb) {
  __shared__ int tmp[256];
  int tid = threadIdx.x;
  int v = (tid < nb) ? bucketCounts[tid] : 0;
  tmp[tid] = v;
  __syncthreads();
#pragma unroll
  for (int off = 1; off < 256; off <<= 1) {
    int t = (tid >= off) ? tmp[tid - off] : 0;
    __syncthreads();
    tmp[tid] += t;
    __syncthreads();
  }
  if (tid < nb) {
    int excl = tmp[tid] - v;
    bucketOffsets[tid] = excl;
    bucketCursor[tid] = excl;
  }
  if (tid == 0) bucketOffsets[nb] = tmp[255];
}

__global__ void bucket_scatter_kernel(const int* __restrict__ src,
                                      const int* __restrict__ dst,
                                      int* __restrict__ bucketCursor,
                                      int2* __restrict__ binEdges,
                                      int nedge, int nb, int tile) {
  __shared__ int hist[256];
  __shared__ int base[256];
  hist[threadIdx.x] = 0;
  __syncthreads();
  int start = blockIdx.x * tile;
  int end = min(start + tile, nedge);
  for (int e = start + threadIdx.x; e < end; e += 256)
    atomicAdd(&hist[dst[e] >> 8], 1);
  __syncthreads();
  if (threadIdx.x < nb) {
    int c = hist[threadIdx.x];
    base[threadIdx.x] = c ? atomicAdd(&bucketCursor[threadIdx.x], c) : 0;
    hist[threadIdx.x] = 0;
  }
  __syncthreads();
  for (int e = start + threadIdx.x; e < end; e += 256) {
    int b = dst[e] >> 8;
    int r = atomicAdd(&hist[b], 1);
    binEdges[base[b] + r] = make_int2(src[e], dst[e]);
  }
}

__global__ void csr_build_kernel(const int2* __restrict__ binEdges,
                                 const int* __restrict__ bucketOffsets,
                                 int2* __restrict__ rowinfo,
                                 int* __restrict__ csr, int n_nodes) {
  __shared__ int hist[256];
  __shared__ int tmp[256];
  int tid = threadIdx.x;
  int b = blockIdx.x;
  int n0 = b << 8;
  int nLoc = min(256, n_nodes - n0);
  int eBase = bucketOffsets[b];
  int cntE = bucketOffsets[b + 1] - eBase;
  hist[tid] = 0;
  __syncthreads();
  for (int i = tid; i < cntE; i += 256)
    atomicAdd(&hist[binEdges[eBase + i].y - n0], 1);
  __syncthreads();
  int v = (tid < nLoc) ? hist[tid] + 1 : 0;  // +1 = self-loop
  tmp[tid] = v;
  __syncthreads();
#pragma unroll
  for (int off = 1; off < 256; off <<= 1) {
    int t = (tid >= off) ? tmp[tid - off] : 0;
    __syncthreads();
    tmp[tid] += t;
    __syncthreads();
  }
  int excl = tmp[tid] - v;
  __syncthreads();
  if (tid < nLoc) {
    int rowStart = eBase + n0 + excl;
    rowinfo[n0 + tid] = make_int2(rowStart, v);
    csr[rowStart] = n0 + tid;  // self edge in slot 0
    hist[tid] = excl + 1;      // local cursor
  }
  __syncthreads();
  for (int i = tid; i < cntE; i += 256) {
    int2 e = binEdges[eBase + i];
    int l = e.y - n0;
    int r = atomicAdd(&hist[l], 1);
    csr[eBase + n0 + r] = e.x;
  }
}

// ========== fused softmax + weighted gather, wave-per-node ==================
// Fast path (deg<=64): no max-subtraction (cancels exactly; e bounded).
// Gather: full chunks of 4 (4 dwordx4 in flight, no wasted loads) + exact
// uniform tail — deg is wave-uniform so all loop tests are s_cbranch.
__global__ void aggregate_kernel(const int2* __restrict__ rowinfo,
                                 const int* __restrict__ csr,
                                 const float* __restrict__ as_,
                                 const float* __restrict__ ad_,
                                 const float* __restrict__ h,
                                 const float* __restrict__ bias,
                                 float* __restrict__ hout, int n_nodes) {
  __shared__ int lds_s[4][64];
  __shared__ float lds_w[4][4 * 68];  // stride 68: conflict-free
  int lane = threadIdx.x & 63;
  int wv = threadIdx.x >> 6;
  int node = (blockIdx.x * blockDim.x + threadIdx.x) >> 6;
  if (node >= n_nodes) return;
  node = __builtin_amdgcn_readfirstlane(node);  // force scalar loads below
  int2 ri = rowinfo[node];
  int row = ri.x;
  int deg = ri.y;
  const float4 ad4 = *(const float4*)(ad_ + node * 4);

  if (deg <= 64) {
    bool valid = lane < deg;
    int s = 0;
    float w0 = 0.f, w1 = 0.f, w2 = 0.f, w3 = 0.f;
    if (valid) {
      s = csr[row + lane];
      const float4 a4 = *(const float4*)(as_ + s * 4);
      w0 = __expf(lrelu(a4.x + ad4.x));
      w1 = __expf(lrelu(a4.y + ad4.y));
      w2 = __expf(lrelu(a4.z + ad4.z));
      w3 = __expf(lrelu(a4.w + ad4.w));
    }
    lds_s[wv][lane] = s;
    lds_w[wv][0 * 68 + lane] = w0;
    lds_w[wv][1 * 68 + lane] = w1;
    lds_w[wv][2 * 68 + lane] = w2;
    lds_w[wv][3 * 68 + lane] = w3;
    // lanes re-split 16x4: 16-lane group g handles edge j = it*4+g, 4 ch/lane
    int grp = lane >> 4;
    int chBase = (lane & 15) * 4;
    int headL = (lane & 15) >> 2;
    const int* sp = &lds_s[wv][0];
    const float* wp = &lds_w[wv][headL * 68];
    float ax = 0.f, ay = 0.f, az = 0.f, aw = 0.f, zacc = 0.f;
    int iters = (deg + 3) >> 2;  // <= 16, wave-uniform
    int it = 0;
    for (; it + 4 <= iters; it += 4) {
      int j0 = it * 4 + grp, j1 = j0 + 4, j2 = j0 + 8, j3 = j0 + 12;
      int s0 = sp[j0], s1 = sp[j1], s2 = sp[j2], s3 = sp[j3];
      float u0 = wp[j0], u1 = wp[j1], u2 = wp[j2], u3 = wp[j3];
      float4 g0 = *(const float4*)(h + (size_t)s0 * 64 + chBase);
      float4 g1 = *(const float4*)(h + (size_t)s1 * 64 + chBase);
      float4 g2 = *(const float4*)(h + (size_t)s2 * 64 + chBase);
      float4 g3 = *(const float4*)(h + (size_t)s3 * 64 + chBase);
      ax = fmaf(u0, g0.x, ax); ay = fmaf(u0, g0.y, ay);
      az = fmaf(u0, g0.z, az); aw = fmaf(u0, g0.w, aw);
      ax = fmaf(u1, g1.x, ax); ay = fmaf(u1, g1.y, ay);
      az = fmaf(u1, g1.z, az); aw = fmaf(u1, g1.w, aw);
      ax = fmaf(u2, g2.x, ax); ay = fmaf(u2, g2.y, ay);
      az = fmaf(u2, g2.z, az); aw = fmaf(u2, g2.w, aw);
      ax = fmaf(u3, g3.x, ax); ay = fmaf(u3, g3.y, ay);
      az = fmaf(u3, g3.z, az); aw = fmaf(u3, g3.w, aw);
      zacc += u0 + u1 + u2 + u3;
    }
    int rem = iters - it;  // 0..3, wave-uniform
    if (rem) {
      int j0 = it * 4 + grp;
      float u0 = wp[j0], u1 = 0.f, u2 = 0.f;
      float4 g1 = make_float4(0.f, 0.f, 0.f, 0.f);
      float4 g2 = make_float4(0.f, 0.f, 0.f, 0.f);
      int s0 = sp[j0];
      float4 g0 = *(const float4*)(h + (size_t)s0 * 64 + chBase);
      if (rem > 1) {
        int j1 = j0 + 4; int s1 = sp[j1]; u1 = wp[j1];
        g1 = *(const float4*)(h + (size_t)s1 * 64 + chBase);
      }
      if (rem > 2) {
        int j2 = j0 + 8; int s2 = sp[j2]; u2 = wp[j2];
        g2 = *(const float4*)(h + (size_t)s2 * 64 + chBase);
      }
      ax = fmaf(u0, g0.x, ax); ay = fmaf(u0, g0.y, ay);
      az = fmaf(u0, g0.z, az); aw = fmaf(u0, g0.w, aw);
      ax = fmaf(u1, g1.x, ax); ay = fmaf(u1, g1.y, ay);
      az = fmaf(u1, g1.z, az); aw = fmaf(u1, g1.w, aw);
      ax = fmaf(u2, g2.x, ax); ay = fmaf(u2, g2.y, ay);
      az = fmaf(u2, g2.z, az); aw = fmaf(u2, g2.w, aw);
      zacc += u0 + u1 + u2;
    }
    // combine the 4 edge-groups (lanes L, L^16, L^32, L^48)
    ax += __shfl_xor(ax, 16); ax += __shfl_xor(ax, 32);
    ay += __shfl_xor(ay, 16); ay += __shfl_xor(ay, 32);
    az += __shfl_xor(az, 16); az += __shfl_xor(az, 32);
    aw += __shfl_xor(aw, 16); aw += __shfl_xor(aw, 32);
    zacc += __shfl_xor(zacc, 16); zacc += __shfl_xor(zacc, 32);
    if (lane < 16) {
      const float4 b4 = *(const float4*)(bias + chBase);
      float4 o;
      o.x = ax / zacc + b4.x;
      o.y = ay / zacc + b4.y;
      o.z = az / zacc + b4.z;
      o.w = aw / zacc + b4.w;
      *(float4*)(hout + (size_t)node * 64 + chBase) = o;
    }
    return;
  }

  // --- slow path (deg > 64): two-pass with max, scalar gather (rare) ---
  int head = lane >> 4;
  float m0 = -INFINITY, m1 = -INFINITY, m2 = -INFINITY, m3 = -INFINITY;
  for (int base = 0; base < deg; base += 64) {
    int idx = base + lane;
    if (idx < deg) {
      int s = csr[row + idx];
      const float4 a4 = *(const float4*)(as_ + s * 4);
      m0 = fmaxf(m0, lrelu(a4.x + ad4.x));
      m1 = fmaxf(m1, lrelu(a4.y + ad4.y));
      m2 = fmaxf(m2, lrelu(a4.z + ad4.z));
      m3 = fmaxf(m3, lrelu(a4.w + ad4.w));
    }
  }
#pragma unroll
  for (int off = 32; off; off >>= 1) {
    m0 = fmaxf(m0, __shfl_xor(m0, off));
    m1 = fmaxf(m1, __shfl_xor(m1, off));
    m2 = fmaxf(m2, __shfl_xor(m2, off));
    m3 = fmaxf(m3, __shfl_xor(m3, off));
  }
  float z0 = 0.f, z1 = 0.f, z2 = 0.f, z3 = 0.f;
  float acc = 0.f;
  for (int base = 0; base < deg; base += 64) {
    int idx = base + lane;
    int s = 0;
    float w0 = 0.f, w1 = 0.f, w2 = 0.f, w3 = 0.f;
    if (idx < deg) {
      s = csr[row + idx];
      const float4 a4 = *(const float4*)(as_ + s * 4);
      w0 = __expf(lrelu(a4.x + ad4.x) - m0);
      w1 = __expf(lrelu(a4.y + ad4.y) - m1);
      w2 = __expf(lrelu(a4.z + ad4.z) - m2);
      w3 = __expf(lrelu(a4.w + ad4.w) - m3);
    }
    z0 += w0; z1 += w1; z2 += w2; z3 += w3;
    lds_s[wv][lane] = s;
    lds_w[wv][0 * 68 + lane] = w0;
    lds_w[wv][1 * 68 + lane] = w1;
    lds_w[wv][2 * 68 + lane] = w2;
    lds_w[wv][3 * 68 + lane] = w3;
    int cnt = min(64, deg - base);
    for (int j = 0; j < cnt; ++j) {
      int sj = lds_s[wv][j];
      float wj = lds_w[wv][head * 68 + j];
      acc = fmaf(wj, h[(size_t)sj * 64 + lane], acc);
    }
  }
#pragma unroll
  for (int off = 32; off; off >>= 1) {
    z0 += __shfl_xor(z0, off);
    z1 += __shfl_xor(z1, off);
    z2 += __shfl_xor(z2, off);
    z3 += __shfl_xor(z3, off);
  }
  float zsel = head == 0 ? z0 : head == 1 ? z1 : head == 2 ? z2 : z3;
  hout[(size_t)node * 64 + lane] = acc / zsel + bias[lane];
}

// =============================== pooling ====================================

__global__ void pool_kernel(const float* __restrict__ h,
                            const int* __restrict__ batch,
                            float* __restrict__ pool,
                            float* __restrict__ cnt, int n_nodes) {
  int lane = threadIdx.x & 63;
  int wave = (blockIdx.x * blockDim.x + threadIdx.x) >> 6;
  int n0 = wave * 16;
  if (n0 >= n_nodes) return;
  int n1 = min(n0 + 16, n_nodes);
  int gcur = batch[n0];
  float acc = 0.f, c_acc = 0.f;
  for (int n = n0; n < n1; ++n) {
    int g = batch[n];
    if (g != gcur) {
      atomicAdd(&pool[gcur * 64 + lane], acc);
      if (lane == 0) atomicAdd(&cnt[gcur], c_acc);
      acc = 0.f; c_acc = 0.f; gcur = g;
    }
    acc += h[(size_t)n * 64 + lane];
    c_acc += 1.f;
  }
  atomicAdd(&pool[gcur * 64 + lane], acc);
  if (lane == 0) atomicAdd(&cnt[gcur], c_acc);
}

__global__ void final_kernel(const float* __restrict__ pool,
                             const float* __restrict__ cnt,
                             const float* __restrict__ Wf,
                             const float* __restrict__ bf,
                             float* __restrict__ out) {
  int g = blockIdx.x;
  int o = threadIdx.x;
  if (o >= 5) return;
  float cg = cnt[g];
  cg = cg > 1.f ? cg : 1.f;
  float acc = bf[o];
  for (int c = 0; c < 64; ++c)
    acc += (pool[g * 64 + c] / cg) * Wf[c * 5 + o];
  out[g * 5 + o] = acc;
}

extern "C" void kernel_launch(void* const* d_in, const int* in_sizes, int n_in,
                              void* d_out, int out_size, void* d_ws, size_t ws_size,
                              hipStream_t stream) {
  const float* x     = (const float*)d_in[0];
  const int*   ei    = (const int*)d_in[1];
  const int*   batch = (const int*)d_in[2];
  const float* W0    = (const float*)d_in[3];
  const float* as0   = (const float*)d_in[4];
  const float* ad0   = (const float*)d_in[5];
  const float* b0    = (const float*)d_in[6];
  const float* Wh    = (const float*)d_in[7];
  const float* ash   = (const float*)d_in[8];
  const float* adh   = (const float*)d_in[9];
  const float* bh    = (const float*)d_in[10];
  const float* Wf    = (const float*)d_in[11];
  const float* bf    = (const float*)d_in[12];
  float* out = (float*)d_out;

  const int N = in_sizes[0];       // 50000
  const int E = in_sizes[1] / 2;   // 800000
  const int* src = ei;
  const int* dst = ei + E;
  const int nE = E + N;
  const int NB = (N + 255) >> 8;   // buckets of 256 nodes (196)

  // workspace layout (binEdges no longer aliases hA: transform0 runs first)
  float* ws  = (float*)d_ws;
  float* hA  = ws;                              // N*64
  float* hB  = hA + (size_t)N * 64;             // N*64
  float* asb = hB + (size_t)N * 64;             // N*4
  float* adb = asb + (size_t)N * 4;             // N*4
  int2* rowinfo = (int2*)(adb + (size_t)N * 4); // N int2
  int* csr     = (int*)(rowinfo + N);           // nE
  int2* binEdges = (int2*)(csr + nE);           // E int2
  float* pool  = (float*)(binEdges + E);        // 64*64
  float* cnt   = pool + NGRAPH * 64;            // 64
  int* bucketCounts  = (int*)(cnt + NGRAPH);    // NB+1
  int* bucketOffsets = bucketCounts + NB + 1;   // NB+1
  int* bucketCursor  = bucketOffsets + NB + 1;  // NB

  const int TILE = 2048;
  const int binBlocks = (E + TILE - 1) / TILE;
  const int nodeWaveBlocks = (N + 3) / 4;
  const int poolWaves = (N + 15) / 16;
  const int poolBlocks = (poolWaves + 3) / 4;

  // ---- fused init + layer-0 transform, then binned CSR build ----
  init_transform0_kernel<<<2048, 256, 0, stream>>>(x, W0, as0, ad0, hA, asb, adb, N,
                                                   bucketCounts, NB, pool, cnt);
  bucket_hist_kernel<<<binBlocks, 256, 0, stream>>>(dst, bucketCounts, E, NB, TILE);
  bucket_scan_kernel<<<1, 256, 0, stream>>>(bucketCounts, bucketOffsets, bucketCursor, NB);
  bucket_scatter_kernel<<<binBlocks, 256, 0, stream>>>(src, dst, bucketCursor, binEdges, E, NB, TILE);
  csr_build_kernel<<<NB, 256, 0, stream>>>(binEdges, bucketOffsets, rowinfo, csr, N);

  for (int layer = 0; layer < 4; ++layer) {
    if (layer > 0) {
      transform_kernel<<<2048, 256, 0, stream>>>(hB, Wh + (size_t)(layer - 1) * 64 * 64,
                                                 ash + (layer - 1) * 64, adh + (layer - 1) * 64,
                                                 hA, asb, adb, N);
    }
    const float* bias = (layer == 0) ? b0 : (bh + (layer - 1) * 64);
    aggregate_kernel<<<nodeWaveBlocks, 256, 0, stream>>>(rowinfo, csr,
                                                         asb, adb, hA, bias, hB, N);
  }

  pool_kernel<<<poolBlocks, 256, 0, stream>>>(hB, batch, pool, cnt, N);
  final_kernel<<<NGRAPH, 64, 0, stream>>>(pool, cnt, Wf, bf, out);
}